// Round 14
// baseline (298.445 us; speedup 1.0000x reference)
//
#include <hip/hip_runtime.h>

typedef unsigned short ushort_t;
typedef __attribute__((ext_vector_type(8))) short short8;
typedef __attribute__((ext_vector_type(4))) float float4v;

#define E_N   4096
#define H_N   512
#define NH_N  4
#define HD_N  128
#define FFN_N 1024
#define H3_N  1536

__device__ __forceinline__ float bf2f(ushort_t u) {
  union { unsigned u; float f; } v; v.u = ((unsigned)u) << 16; return v.f;
}
__device__ __forceinline__ ushort_t f2bf(float f) {
  union { float f; unsigned u; } v; v.f = f;
  unsigned r = v.u + 0x7fffu + ((v.u >> 16) & 1u);
  return (ushort_t)(r >> 16);
}
// 8 consecutive fp32 -> 8 bf16 packed into uint4
__device__ __forceinline__ uint4 cvt8(const float* p) {
  float4 a = *(const float4*)p;
  float4 b = *(const float4*)(p + 4);
  union { ushort_t u[8]; uint4 v; } pk;
  pk.u[0] = f2bf(a.x); pk.u[1] = f2bf(a.y); pk.u[2] = f2bf(a.z); pk.u[3] = f2bf(a.w);
  pk.u[4] = f2bf(b.x); pk.u[5] = f2bf(b.y); pk.u[6] = f2bf(b.z); pk.u[7] = f2bf(b.w);
  return pk.v;
}

// global(16B/lane) -> LDS DMA: no VGPR payload (spill mechanism cannot occur)
__device__ __forceinline__ void gload16(const void* g, void* l) {
  __builtin_amdgcn_global_load_lds(
      (const __attribute__((address_space(1))) unsigned*)g,
      (__attribute__((address_space(3))) unsigned*)l, 16, 0, 0);
}

// ---------------------------------------------------------------------------
// prep: fused {zero agg (blocks 0..2047)} + {fp32->bf16 convert of x + all
// weights (blocks 2048..4863)}.
// ---------------------------------------------------------------------------
__global__ __launch_bounds__(256) void prep_kernel(
    const float* __restrict__ x,
    const float* __restrict__ wmsg, const float* __restrict__ wih,
    const float* __restrict__ whh,  const float* __restrict__ win,
    const float* __restrict__ wout, const float* __restrict__ wlin,
    const float* __restrict__ wf1,  ushort_t* __restrict__ dst,
    float4* __restrict__ agg)
{
  int b = blockIdx.x;
  if (b < 2048) {
    agg[(size_t)b * 256 + threadIdx.x] = make_float4(0.f, 0.f, 0.f, 0.f);
    return;
  }
  size_t o = ((size_t)(b - 2048) * 256 + threadIdx.x) * 8;
  const float* s;
  if      (o < 2097152) s = x    + o;
  else if (o < 2359296) s = wmsg + (o - 2097152);
  else if (o < 3145728) s = wih  + (o - 2359296);
  else if (o < 3932160) s = whh  + (o - 3145728);
  else if (o < 4718592) s = win  + (o - 3932160);
  else if (o < 4980736) s = wout + (o - 4718592);
  else if (o < 5242880) s = wlin + (o - 4980736);
  else                  s = wf1  + (o - 5242880);
  *(uint4*)(dst + o) = cvt8(s);
}

// agg fp32 -> bf16 (runs after MSG's atomics complete)
__global__ __launch_bounds__(256) void cvt_agg_kernel(
    const float* __restrict__ agg, ushort_t* __restrict__ aggb) {
  size_t o = ((size_t)blockIdx.x * 256 + threadIdx.x) * 8;
  *(uint4*)(aggb + o) = cvt8(agg + o);
}

// deterministic F1 reduce: out[row] = b2 + sum_k pf[row][k] (fixed order)
__global__ __launch_bounds__(256) void f2red_kernel(
    const float* __restrict__ pf, const float* __restrict__ b2,
    float* __restrict__ out) {
  int i = blockIdx.x * 256 + threadIdx.x;   // 0..4095
  float s = b2[0];
#pragma unroll
  for (int k = 0; k < 32; k++) s += pf[(size_t)i * 32 + k];
  out[i] = s;
}

// ---------------------------------------------------------------------------
// bf16-MFMA GEMM (DMA-staged): BM x 64 tile, BK=64, 4 waves,
// global_load_lds double-buffer, ONE barrier/iter, rule-#21 swizzle
// (linear LDS dest + pre-swizzled global source, XOR byte^((row&7)<<4)).
// BM=64 -> launch_bounds(256,4) (32 KB LDS, 4 blocks/CU).
// GIGH fusion permanently dropped: caused aliasing bugs twice (r10, r13);
// every 4 MB scratch region in [1,33) is live during that fused window.
// MODE_QKV: q part pre-scaled by 1/sqrt(128) (scale folded out of attn).
// MODE_F1: deterministic partial store (f2red sums in fixed order).
// ---------------------------------------------------------------------------
enum { MODE_MSG = 0, MODE_GI = 1, MODE_GH = 2, MODE_QKV = 3, MODE_OUT = 4,
       MODE_LIN = 5, MODE_F1 = 6 };

template <int MODE, int BM>
__global__ __launch_bounds__(256, (BM == 64 ? 4 : 3)) void gemm_bt(
    const ushort_t* __restrict__ A, const ushort_t* __restrict__ W,
    const float* __restrict__ bias, int K,
    float* __restrict__ outf, ushort_t* __restrict__ outb,
    const int* __restrict__ edge, float* __restrict__ aggf,
    const ushort_t* __restrict__ hres,
    ushort_t* __restrict__ qb, ushort_t* __restrict__ kb,
    ushort_t* __restrict__ vt, const float* __restrict__ wf2)
{
  constexpr int MI   = BM / 32;       // 16-row A fragments per wave
  constexpr int ASZ  = BM * 128;      // bytes per A buffer
  constexpr int BSZ  = 64 * 128;      // bytes per B buffer
  constexpr int NCHA = BM / 8;        // 1024-B A chunks per tile
  constexpr int NCH  = NCHA + 8;      // + 8 B chunks

  __shared__ ushort_t As[2][BM * 64];
  __shared__ ushort_t Bs[2][64 * 64];

  const int tid  = threadIdx.x;
  const int lane = tid & 63;
  const int wave = tid >> 6;
  const int quad = lane >> 4;
  const int l15  = lane & 15;
  const int m0 = blockIdx.x * BM;
  const int n0 = blockIdx.y * 64;
  const int wm = (wave >> 1) * (BM / 2);
  const int wn = (wave & 1) * 32;
  const int rmask = (l15 & 7) << 4;   // read-side swizzle mask

  // DMA chunk coords: chunk = 8 rows x 128 B; lane covers row lane>>3,
  // 16 B at byte (lane&7)*16; source col pre-swizzled by ((row&7)<<4).
  const int crow  = lane >> 3;                              // 0..7
  const int selem = ((((lane & 7) * 16)) ^ (crow << 4)) >> 1;

  float4v acc[MI][2];
#pragma unroll
  for (int i = 0; i < MI; i++)
#pragma unroll
    for (int j = 0; j < 2; j++)
#pragma unroll
      for (int r = 0; r < 4; r++) acc[i][j][r] = 0.f;

#define ISSUE(KK, BUF)                                                         \
  do {                                                                         \
    _Pragma("unroll")                                                          \
    for (int j_ = 0; j_ < NCH / 4; j_++) {                                     \
      const int c_ = wave + j_ * 4;                                            \
      if (c_ < NCHA) {                                                         \
        const int row_ = c_ * 8 + crow;                                        \
        gload16(A + (size_t)(m0 + row_) * K + (KK) + selem,                    \
                (char*)As + (BUF) * ASZ + c_ * 1024);                          \
      } else {                                                                 \
        const int row_ = (c_ - NCHA) * 8 + crow;                               \
        gload16(W + (size_t)(n0 + row_) * K + (KK) + selem,                    \
                (char*)Bs + (BUF) * BSZ + (c_ - NCHA) * 1024);                 \
      }                                                                        \
    }                                                                          \
  } while (0)

  ISSUE(0, 0);
  int cur = 0;

  for (int k0 = 0; k0 < K; k0 += 64) {
    __syncthreads();   // drains DMA (buf cur ready) + prev reads of cur^1 done
    if (k0 + 64 < K) ISSUE(k0 + 64, cur ^ 1);

#pragma unroll
    for (int ks = 0; ks < 2; ks++) {
      short8 af[MI], bfr[2];
#pragma unroll
      for (int i = 0; i < MI; i++)
        af[i] = *(const short8*)((char*)As + cur * ASZ +
                 (wm + i * 16 + l15) * 128 + ((ks * 64 + quad * 16) ^ rmask));
#pragma unroll
      for (int j = 0; j < 2; j++)
        bfr[j] = *(const short8*)((char*)Bs + cur * BSZ +
                 (wn + j * 16 + l15) * 128 + ((ks * 64 + quad * 16) ^ rmask));
#pragma unroll
      for (int i = 0; i < MI; i++)
#pragma unroll
        for (int j = 0; j < 2; j++)
          acc[i][j] = __builtin_amdgcn_mfma_f32_16x16x32_bf16(af[i], bfr[j],
                                                              acc[i][j], 0, 0, 0);
    }
    cur ^= 1;
  }
#undef ISSUE

  if constexpr (MODE == MODE_F1) {
    // deterministic partial: pf[row][ny*2 + (wave&1)] (plain store, no atomics)
    float fsum[MI][4];
#pragma unroll
    for (int i = 0; i < MI; i++)
#pragma unroll
      for (int r = 0; r < 4; r++) fsum[i][r] = 0.f;
#pragma unroll
    for (int j = 0; j < 2; j++) {
      const int col = n0 + wn + j * 16 + l15;
      const float bv = bias[col];
      const float wv = wf2[col];
#pragma unroll
      for (int i = 0; i < MI; i++)
#pragma unroll
        for (int r = 0; r < 4; r++)
          fsum[i][r] += fmaxf(acc[i][j][r] + bv, 0.f) * wv;
    }
#pragma unroll
    for (int i = 0; i < MI; i++)
#pragma unroll
      for (int r = 0; r < 4; r++) {
        float s = fsum[i][r];
        s += __shfl_xor(s, 1, 64); s += __shfl_xor(s, 2, 64);
        s += __shfl_xor(s, 4, 64); s += __shfl_xor(s, 8, 64);
        if (l15 == 0)
          outf[(size_t)(m0 + wm + i * 16 + quad * 4 + r) * 32 +
               blockIdx.y * 2 + (wave & 1)] = s;
      }
  } else {
#pragma unroll
    for (int j = 0; j < 2; j++) {
      const int col = n0 + wn + j * 16 + l15;
      const float bv = bias[col];
#pragma unroll
      for (int i = 0; i < MI; i++) {
#pragma unroll
        for (int r = 0; r < 4; r++) {
          const int row = m0 + wm + i * 16 + quad * 4 + r;
          float v = acc[i][j][r] + bv;
          if constexpr (MODE == MODE_MSG) {
            v = fmaxf(v, 0.f);
            const int dst = edge[E_N + row] & (E_N - 1);  // edge_index[1][row]
            atomicAdd(&aggf[(size_t)dst * H_N + col], v);
          } else if constexpr (MODE == MODE_GI || MODE == MODE_GH) {
            outb[(size_t)row * H3_N + col] = f2bf(v);
          } else if constexpr (MODE == MODE_QKV) {
            const int part = col >> 9;         // 0=q 1=k 2=v
            const int hh   = (col >> 7) & 3;
            const int d    = col & 127;
            // fold 1/sqrt(128) into q so attn needn't scale per-iter
            if (part == 0) v *= 0.088388347648318447f;
            const ushort_t bvv = f2bf(v);
            if (part == 0)      qb[((size_t)hh * E_N + row) * HD_N + d] = bvv;
            else if (part == 1) kb[((size_t)hh * E_N + row) * HD_N + d] = bvv;
            else                vt[((size_t)hh * HD_N + d) * E_N + row] = bvv;  // V^T
          } else if constexpr (MODE == MODE_OUT) {
            v += bf2f(hres[(size_t)row * H_N + col]);   // residual y = o + h
            outf[(size_t)row * H_N + col] = v;
          } else {  // MODE_LIN
            outb[(size_t)row * H_N + col] = f2bf(fmaxf(v, 0.f));
          }
        }
      }
    }
  }
}

// ---------------------------------------------------------------------------
// Flash attention (r8-exact structure; Q pre-scaled so no per-iter scale mul):
// K/V staged via global_load_lds DMA (zero VGPR payload), double-buffered,
// ONE barrier per KV iteration; rule-#21 swizzle; head = bid&3 -> one head
// per XCD (K/V L2-resident).  8 waves; waves 0-3: KV [0,2048), waves 4-7:
// KV [2048,4096); in-LDS flash merge at end.
// ---------------------------------------------------------------------------
__global__ __launch_bounds__(512, 2) void attn_kernel(
    const ushort_t* __restrict__ Qg, const ushort_t* __restrict__ Kg,
    const ushort_t* __restrict__ Vtg, ushort_t* __restrict__ Ob)
{
  const int bid  = blockIdx.x;
  const int head = bid & 3;
  const int qb0  = (bid >> 2) * 64;
  const int tid  = threadIdx.x;
  const int wave = tid >> 6;
  const int grp  = wave >> 2;     // 0/1: which KV half
  const int w4   = wave & 3;      // which 16-row Q sub-tile / staging chunk set
  const int lane = tid & 63;
  const int quad = lane >> 4;
  const int l15  = lane & 15;

  __shared__ ushort_t Ks[2][2][64][128];   // [grp][buf], swizzled, 65536 B
  __shared__ ushort_t Vs[2][2][128][64];   // [grp][buf], swizzled, 65536 B
  __shared__ ushort_t Ps[8][16][64];       // per-wave, swizzled, 16384 B
  char* Psc = (char*)Ps + wave * 2048;

  const ushort_t* Qhead  = Qg  + (size_t)head * E_N * HD_N;
  const ushort_t* Khead  = Kg  + (size_t)head * E_N * HD_N;
  const ushort_t* Vthead = Vtg + (size_t)head * HD_N * E_N;

  // Q A-fragments: loop-invariant, in registers (pre-scaled by 1/sqrt(128)).
  short8 aq[4];
#pragma unroll
  for (int ks = 0; ks < 4; ks++)
    aq[ks] = *(const short8*)(Qhead +
        (size_t)(qb0 + w4 * 16 + l15) * HD_N + ks * 32 + quad * 8);

  float4v oacc[8];
#pragma unroll
  for (int i = 0; i < 8; i++)
#pragma unroll
    for (int r = 0; r < 4; r++) oacc[i][r] = 0.f;
  float mprev[4], lsum[4];
#pragma unroll
  for (int r = 0; r < 4; r++) { mprev[r] = -1e30f; lsum[r] = 0.f; }

  const int q15sw = (l15 & 7) << 4;           // read-side swizzle mask
  const int kt0 = grp * 2048;

#define ISSUE(KT, BUF)                                                         \
  do {                                                                         \
    char* kb_ = (char*)Ks + ((grp * 2 + (BUF)) << 14);                         \
    char* vb_ = (char*)Vs + ((grp * 2 + (BUF)) << 14);                         \
    _Pragma("unroll")                                                          \
    for (int i_ = 0; i_ < 4; i_++) {                                           \
      const int c_ = w4 * 4 + i_;                                              \
      const int krow_ = 4 * c_ + (lane >> 4);      /* tile row 0..63 */        \
      gload16(Khead + (size_t)((KT) + krow_) * HD_N +                          \
                  (((((lane & 15) * 16)) ^ ((krow_ & 7) << 4)) >> 1),          \
              kb_ + c_ * 1024);                                                \
      const int vrow_ = 8 * c_ + (lane >> 3);      /* tile row 0..127 */       \
      gload16(Vthead + (size_t)vrow_ * E_N + (KT) +                            \
                  (((((lane & 7) * 16)) ^ ((lane >> 3) << 4)) >> 1),           \
              vb_ + c_ * 1024);                                                \
    }                                                                          \
  } while (0)

  ISSUE(kt0, 0);   // prologue: tile 0
  int cur = 0;

  for (int it = 0; it < 32; it++) {
    __syncthreads();   // drains DMA (tile it ready) + tile it-1 reads done
    if (it + 1 < 32) ISSUE(kt0 + (it + 1) * 64, cur ^ 1);

    const char* kt_ = (char*)Ks + ((grp * 2 + cur) << 14);
    const char* vt_ = (char*)Vs + ((grp * 2 + cur) << 14);

    float4v sacc[4];
#pragma unroll
    for (int j = 0; j < 4; j++)
#pragma unroll
      for (int r = 0; r < 4; r++) sacc[j][r] = 0.f;
#pragma unroll
    for (int ks = 0; ks < 4; ks++) {
#pragma unroll
      for (int j = 0; j < 4; j++) {
        short8 bk = *(const short8*)(kt_ + (j * 16 + l15) * 256 +
                                     ((ks * 64 + quad * 16) ^ q15sw));
        sacc[j] = __builtin_amdgcn_mfma_f32_16x16x32_bf16(aq[ks], bk, sacc[j], 0, 0, 0);
      }
    }

    float alpha[4], pv[4][4];
#pragma unroll
    for (int r = 0; r < 4; r++) {
      float mx = -1e30f;
#pragma unroll
      for (int j = 0; j < 4; j++) { float s = sacc[j][r]; pv[j][r] = s; mx = fmaxf(mx, s); }
#pragma unroll
      for (int off = 1; off < 16; off <<= 1) mx = fmaxf(mx, __shfl_xor(mx, off, 64));
      float mnew = fmaxf(mprev[r], mx);
      alpha[r] = __expf(mprev[r] - mnew);
      float ss = 0.f;
#pragma unroll
      for (int j = 0; j < 4; j++) { float p = __expf(pv[j][r] - mnew); pv[j][r] = p; ss += p; }
#pragma unroll
      for (int off = 1; off < 16; off <<= 1) ss += __shfl_xor(ss, off, 64);
      lsum[r] = lsum[r] * alpha[r] + ss;
      mprev[r] = mnew;
    }
#pragma unroll
    for (int i = 0; i < 8; i++)
#pragma unroll
      for (int r = 0; r < 4; r++) oacc[i][r] *= alpha[r];

    // Ps write (wave-private, swizzled): within-wave lgkmcnt order, no barrier
#pragma unroll
    for (int j = 0; j < 4; j++)
#pragma unroll
      for (int r = 0; r < 4; r++) {
        const int prow = quad * 4 + r;
        *(ushort_t*)(Psc + prow * 128 +
                     ((2 * (j * 16 + l15)) ^ ((prow & 7) << 4))) = f2bf(pv[j][r]);
      }

#pragma unroll
    for (int ks2 = 0; ks2 < 2; ks2++) {
      short8 ap = *(const short8*)(Psc + l15 * 128 +
                                   ((ks2 * 64 + quad * 16) ^ q15sw));
#pragma unroll
      for (int j = 0; j < 8; j++) {
        short8 bv = *(const short8*)(vt_ + (j * 16 + l15) * 128 +
                                     ((ks2 * 64 + quad * 16) ^ q15sw));
        oacc[j] = __builtin_amdgcn_mfma_f32_16x16x32_bf16(ap, bv, oacc[j], 0, 0, 0);
      }
    }
    cur ^= 1;
  }
#undef ISSUE

  // ---- merge the two KV halves (flash combine), group1 -> LDS -> group0 ----
  __syncthreads();
  float* mO  = (float*)Ks;   // [64][128] fp32 = 32768 B (Ks region is 64 KB)
  float* mML = (float*)Vs;   // [64][2]   fp32
  if (grp == 1) {
#pragma unroll
    for (int j = 0; j < 8; j++)
#pragma unroll
      for (int r = 0; r < 4; r++)
        mO[(w4 * 16 + quad * 4 + r) * 128 + j * 16 + l15] = oacc[j][r];
    if (l15 == 0) {
#pragma unroll
      for (int r = 0; r < 4; r++) {
        mML[(w4 * 16 + quad * 4 + r) * 2 + 0] = mprev[r];
        mML[(w4 * 16 + quad * 4 + r) * 2 + 1] = lsum[r];
      }
    }
  }
  __syncthreads();
  if (grp == 0) {
    float s0[4], s1[4];
#pragma unroll
    for (int r = 0; r < 4; r++) {
      int rr = w4 * 16 + quad * 4 + r;
      float m1 = mML[rr * 2 + 0], l1 = mML[rr * 2 + 1];
      float m  = fmaxf(mprev[r], m1);
      float e0 = __expf(mprev[r] - m);
      float e1 = __expf(m1 - m);
      float inv = 1.f / (lsum[r] * e0 + l1 * e1);
      s0[r] = e0 * inv;
      s1[r] = e1 * inv;
    }
#pragma unroll
    for (int j = 0; j < 8; j++)
#pragma unroll
      for (int r = 0; r < 4; r++) {
        int row = qb0 + w4 * 16 + quad * 4 + r;
        int col = head * HD_N + j * 16 + l15;
        float o1 = mO[(w4 * 16 + quad * 4 + r) * 128 + j * 16 + l15];
        Ob[(size_t)row * H_N + col] = f2bf(oacc[j][r] * s0[r] + o1 * s1[r]);
      }
  }
}

// ---------------------------------------------------------------------------
// GRU elementwise, vectorized: each thread handles 8 contiguous cols.
__global__ __launch_bounds__(256) void gru_kernel(
    const ushort_t* __restrict__ gib, const ushort_t* __restrict__ ghb,
    const float* __restrict__ x, ushort_t* __restrict__ hb) {
  int t = blockIdx.x * 256 + threadIdx.x;         // E*H/8 threads
  int e = t >> 6, j8 = (t & 63) * 8;
  size_t b = (size_t)e * H3_N + j8;
  short8 vir = *(const short8*)(gib + b);
  short8 viz = *(const short8*)(gib + b + 512);
  short8 vin = *(const short8*)(gib + b + 1024);
  short8 vhr = *(const short8*)(ghb + b);
  short8 vhz = *(const short8*)(ghb + b + 512);
  short8 vhn = *(const short8*)(ghb + b + 1024);
  size_t xo = (size_t)e * H_N + j8;
  float4 x0 = *(const float4*)(x + xo);
  float4 x1 = *(const float4*)(x + xo + 4);
  float xv[8] = {x0.x, x0.y, x0.z, x0.w, x1.x, x1.y, x1.z, x1.w};
  union { ushort_t u[8]; uint4 v; } o;
#pragma unroll
  for (int i = 0; i < 8; i++) {
    float ir = bf2f((ushort_t)vir[i]), iz = bf2f((ushort_t)viz[i]), inn = bf2f((ushort_t)vin[i]);
    float hr = bf2f((ushort_t)vhr[i]), hz = bf2f((ushort_t)vhz[i]), hn  = bf2f((ushort_t)vhn[i]);
    float r = 1.f / (1.f + __expf(-(ir + hr)));
    float z = 1.f / (1.f + __expf(-(iz + hz)));
    float n = tanhf(inn + r * hn);
    o.u[i] = f2bf((1.f - z) * n + z * xv[i]);
  }
  *(uint4*)(hb + xo) = o.v;
}

__global__ __launch_bounds__(256) void ln_kernel(
    const float* __restrict__ y, const float* __restrict__ g,
    const float* __restrict__ b, ushort_t* __restrict__ yn) {
  int wave = threadIdx.x >> 6, lane = threadIdx.x & 63;
  int row = blockIdx.x * 4 + wave;
  const float* yr = y + (size_t)row * H_N;
  float v[8], s = 0.f;
#pragma unroll
  for (int i = 0; i < 8; i++) { v[i] = yr[lane + i * 64]; s += v[i]; }
#pragma unroll
  for (int off = 1; off < 64; off <<= 1) s += __shfl_xor(s, off, 64);
  float mu = s * (1.f / 512.f);
  float q = 0.f;
#pragma unroll
  for (int i = 0; i < 8; i++) { float d = v[i] - mu; q += d * d; }
#pragma unroll
  for (int off = 1; off < 64; off <<= 1) q += __shfl_xor(q, off, 64);
  float rstd = rsqrtf(q * (1.f / 512.f) + 1e-5f);
#pragma unroll
  for (int i = 0; i < 8; i++) {
    int c = lane + i * 64;
    yn[(size_t)row * H_N + c] = f2bf((v[i] - mu) * rstd * g[c] + b[c]);
  }
}

// ---------------------------------------------------------------------------
extern "C" void kernel_launch(void* const* d_in, const int* in_sizes, int n_in,
                              void* d_out, int out_size, void* d_ws, size_t ws_size,
                              hipStream_t stream) {
  const float* x     = (const float*)d_in[0];
  const int*   edge  = (const int*)d_in[1];
  const float* W_msg = (const float*)d_in[2];
  const float* b_msg = (const float*)d_in[3];
  const float* W_ih  = (const float*)d_in[4];
  const float* b_ih  = (const float*)d_in[5];
  const float* W_hh  = (const float*)d_in[6];
  const float* b_hh  = (const float*)d_in[7];
  const float* W_in  = (const float*)d_in[8];
  const float* b_in  = (const float*)d_in[9];
  const float* W_out = (const float*)d_in[10];
  const float* b_out = (const float*)d_in[11];
  const float* ln_g  = (const float*)d_in[12];
  const float* ln_b  = (const float*)d_in[13];
  const float* W_lin = (const float*)d_in[14];
  const float* b_lin = (const float*)d_in[15];
  const float* W_f1  = (const float*)d_in[16];
  const float* b_f1  = (const float*)d_in[17];
  const float* W_f2  = (const float*)d_in[18];
  const float* b_f2  = (const float*)d_in[19];

  char* ws = (char*)d_ws;
  const size_t MB = 1024 * 1024;
  // Workspace: r12-exact map (tripwire-proven).  Launch ORDER matters:
  // GI (reads aggb [29,33)) must complete before GH (writes ghb [21,33)).
  float*    agg  = (float*)(ws + 1 * MB);          // [1,9)   prep..cvt_agg
  ushort_t* hb   = (ushort_t*)(ws + 1 * MB);       // [1,5)   gru..OUT (agg dead)
  ushort_t* gib  = (ushort_t*)(ws + 9 * MB);       // [9,21)  bf16 [E][3H], GI..gru
  ushort_t* ghb  = (ushort_t*)(ws + 21 * MB);      // [21,33) bf16 [E][3H], GH..gru
  ushort_t* Qb   = (ushort_t*)(ws + 5 * MB);       // [5,9)   QKV..attn
  ushort_t* Kb   = (ushort_t*)(ws + 9 * MB);       // [9,13)  (gib dead)
  ushort_t* Vt   = (ushort_t*)(ws + 13 * MB);      // [13,17)
  ushort_t* ob   = (ushort_t*)(ws + 17 * MB);      // [17,21) attn..OUT
  float*    y    = (float*)(ws + 21 * MB);         // [21,29) fp32, OUT..ln (ghb dead)
  ushort_t* ynb  = (ushort_t*)(ws + 29 * MB);      // [29,31) ln..LIN
  ushort_t* gb   = (ushort_t*)(ws + 31 * MB);      // [31,33) LIN..F1
  ushort_t* aggb = (ushort_t*)(ws + 29 * MB);      // [29,33) cvt_agg..GI (GH after)
  float*    pf   = (float*)(ws + 21 * MB);         // [21,21.5) F1..f2red (y dead)
  ushort_t* xb   = (ushort_t*)(ws + 33 * MB);      // [33,37) bf16 x
  ushort_t* Wmsg_b = xb + 2097152;                 // weights bf16, contiguous
  ushort_t* Wih_b  = xb + 2359296;
  ushort_t* Whh_b  = xb + 3145728;
  ushort_t* Win_b  = xb + 3932160;
  ushort_t* Wout_b = xb + 4718592;
  ushort_t* Wlin_b = xb + 4980736;
  ushort_t* Wf1_b  = xb + 5242880;

  prep_kernel<<<4864, 256, 0, stream>>>(
      x, W_msg, W_ih, W_hh, W_in, W_out, W_lin, W_f1, xb, (float4*)agg);

  gemm_bt<MODE_MSG, 64><<<dim3(64, 8), 256, 0, stream>>>(
      xb, Wmsg_b, b_msg, H_N, nullptr, nullptr, edge, agg, nullptr,
      nullptr, nullptr, nullptr, nullptr);

  cvt_agg_kernel<<<1024, 256, 0, stream>>>(agg, aggb);

  gemm_bt<MODE_GI, 64><<<dim3(64, 24), 256, 0, stream>>>(
      aggb, Wih_b, b_ih, H_N, nullptr, gib, nullptr, nullptr, nullptr,
      nullptr, nullptr, nullptr, nullptr);

  gemm_bt<MODE_GH, 64><<<dim3(64, 24), 256, 0, stream>>>(
      xb, Whh_b, b_hh, H_N, nullptr, ghb, nullptr, nullptr, nullptr,
      nullptr, nullptr, nullptr, nullptr);

  gru_kernel<<<1024, 256, 0, stream>>>(gib, ghb, x, hb);

  gemm_bt<MODE_QKV, 64><<<dim3(64, 24), 256, 0, stream>>>(
      hb, Win_b, b_in, H_N, nullptr, nullptr, nullptr, nullptr, nullptr,
      Qb, Kb, Vt, nullptr);

  attn_kernel<<<256, 512, 0, stream>>>(Qb, Kb, Vt, ob);

  gemm_bt<MODE_OUT, 64><<<dim3(64, 8), 256, 0, stream>>>(
      ob, Wout_b, b_out, H_N, y, nullptr, nullptr, nullptr, hb,
      nullptr, nullptr, nullptr, nullptr);

  ln_kernel<<<1024, 256, 0, stream>>>(y, ln_g, ln_b, ynb);

  gemm_bt<MODE_LIN, 64><<<dim3(64, 8), 256, 0, stream>>>(
      ynb, Wlin_b, b_lin, H_N, nullptr, gb, nullptr, nullptr, nullptr,
      nullptr, nullptr, nullptr, nullptr);

  gemm_bt<MODE_F1, 64><<<dim3(64, 16), 256, 0, stream>>>(
      gb, Wf1_b, b_f1, H_N, pf, nullptr, nullptr, nullptr, nullptr,
      nullptr, nullptr, nullptr, W_f2);

  f2red_kernel<<<16, 256, 0, stream>>>(pf, b_f2, (float*)d_out);
}

// Round 15
// 290.265 us; speedup vs baseline: 1.0282x; 1.0282x over previous
//
#include <hip/hip_runtime.h>

typedef unsigned short ushort_t;
typedef __attribute__((ext_vector_type(8))) short short8;
typedef __attribute__((ext_vector_type(4))) float float4v;

#define E_N   4096
#define H_N   512
#define NH_N  4
#define HD_N  128
#define FFN_N 1024
#define H3_N  1536

__device__ __forceinline__ float bf2f(ushort_t u) {
  union { unsigned u; float f; } v; v.u = ((unsigned)u) << 16; return v.f;
}
__device__ __forceinline__ ushort_t f2bf(float f) {
  union { float f; unsigned u; } v; v.f = f;
  unsigned r = v.u + 0x7fffu + ((v.u >> 16) & 1u);
  return (ushort_t)(r >> 16);
}
// 8 consecutive fp32 -> 8 bf16 packed into uint4
__device__ __forceinline__ uint4 cvt8(const float* p) {
  float4 a = *(const float4*)p;
  float4 b = *(const float4*)(p + 4);
  union { ushort_t u[8]; uint4 v; } pk;
  pk.u[0] = f2bf(a.x); pk.u[1] = f2bf(a.y); pk.u[2] = f2bf(a.z); pk.u[3] = f2bf(a.w);
  pk.u[4] = f2bf(b.x); pk.u[5] = f2bf(b.y); pk.u[6] = f2bf(b.z); pk.u[7] = f2bf(b.w);
  return pk.v;
}

// global(16B/lane) -> LDS DMA: no VGPR payload (spill mechanism cannot occur)
__device__ __forceinline__ void gload16(const void* g, void* l) {
  __builtin_amdgcn_global_load_lds(
      (const __attribute__((address_space(1))) unsigned*)g,
      (__attribute__((address_space(3))) unsigned*)l, 16, 0, 0);
}

// ---------------------------------------------------------------------------
// prep: fused {zero agg (blocks 0..2047)} + {fp32->bf16 convert of x + all
// weights (blocks 2048..4863)}.
// ---------------------------------------------------------------------------
__global__ __launch_bounds__(256) void prep_kernel(
    const float* __restrict__ x,
    const float* __restrict__ wmsg, const float* __restrict__ wih,
    const float* __restrict__ whh,  const float* __restrict__ win,
    const float* __restrict__ wout, const float* __restrict__ wlin,
    const float* __restrict__ wf1,  ushort_t* __restrict__ dst,
    float4* __restrict__ agg)
{
  int b = blockIdx.x;
  if (b < 2048) {
    agg[(size_t)b * 256 + threadIdx.x] = make_float4(0.f, 0.f, 0.f, 0.f);
    return;
  }
  size_t o = ((size_t)(b - 2048) * 256 + threadIdx.x) * 8;
  const float* s;
  if      (o < 2097152) s = x    + o;
  else if (o < 2359296) s = wmsg + (o - 2097152);
  else if (o < 3145728) s = wih  + (o - 2359296);
  else if (o < 3932160) s = whh  + (o - 3145728);
  else if (o < 4718592) s = win  + (o - 3932160);
  else if (o < 4980736) s = wout + (o - 4718592);
  else if (o < 5242880) s = wlin + (o - 4980736);
  else                  s = wf1  + (o - 5242880);
  *(uint4*)(dst + o) = cvt8(s);
}

// agg fp32 -> bf16 (runs after MSG's atomics complete)
__global__ __launch_bounds__(256) void cvt_agg_kernel(
    const float* __restrict__ agg, ushort_t* __restrict__ aggb) {
  size_t o = ((size_t)blockIdx.x * 256 + threadIdx.x) * 8;
  *(uint4*)(aggb + o) = cvt8(agg + o);
}

// deterministic F1 reduce: out[row] = b2 + sum_k pf[row][k] (fixed order)
__global__ __launch_bounds__(256) void f2red_kernel(
    const float* __restrict__ pf, const float* __restrict__ b2,
    float* __restrict__ out) {
  int i = blockIdx.x * 256 + threadIdx.x;   // 0..4095
  float s = b2[0];
#pragma unroll
  for (int k = 0; k < 32; k++) s += pf[(size_t)i * 32 + k];
  out[i] = s;
}

// ---------------------------------------------------------------------------
// bf16-MFMA GEMM (DMA-staged): BM x 64 tile, BK=64, 4 waves,
// global_load_lds double-buffer, ONE barrier/iter, rule-#21 swizzle
// (linear LDS dest + pre-swizzled global source, XOR byte^((row&7)<<4)).
// Tile choice is SHAPE-DEPENDENT (r9/r14 A/B): BM=128 for wide GEMMs
// (grid.y=24: GI/GH/QKV -- 16 MFMA/wave/iter amortizes barrier+DMA) and
// BM=64 for narrow N=512 GEMMs (MSG/OUT/LIN/F1 -- 4 blocks/CU fixes the
// 1-block/CU starvation).  GIGH fusion permanently dropped (r10/r13 bugs).
// MODE_QKV: q part pre-scaled by 1/sqrt(128).
// MODE_F1: deterministic partial store (f2red sums in fixed order).
// ---------------------------------------------------------------------------
enum { MODE_MSG = 0, MODE_GI = 1, MODE_GH = 2, MODE_QKV = 3, MODE_OUT = 4,
       MODE_LIN = 5, MODE_F1 = 6 };

template <int MODE, int BM>
__global__ __launch_bounds__(256, (BM == 64 ? 4 : 3)) void gemm_bt(
    const ushort_t* __restrict__ A, const ushort_t* __restrict__ W,
    const float* __restrict__ bias, int K,
    float* __restrict__ outf, ushort_t* __restrict__ outb,
    const int* __restrict__ edge, float* __restrict__ aggf,
    const ushort_t* __restrict__ hres,
    ushort_t* __restrict__ qb, ushort_t* __restrict__ kb,
    ushort_t* __restrict__ vt, const float* __restrict__ wf2)
{
  constexpr int MI   = BM / 32;       // 16-row A fragments per wave
  constexpr int ASZ  = BM * 128;      // bytes per A buffer
  constexpr int BSZ  = 64 * 128;      // bytes per B buffer
  constexpr int NCHA = BM / 8;        // 1024-B A chunks per tile
  constexpr int NCH  = NCHA + 8;      // + 8 B chunks

  __shared__ ushort_t As[2][BM * 64];
  __shared__ ushort_t Bs[2][64 * 64];

  const int tid  = threadIdx.x;
  const int lane = tid & 63;
  const int wave = tid >> 6;
  const int quad = lane >> 4;
  const int l15  = lane & 15;
  const int m0 = blockIdx.x * BM;
  const int n0 = blockIdx.y * 64;
  const int wm = (wave >> 1) * (BM / 2);
  const int wn = (wave & 1) * 32;
  const int rmask = (l15 & 7) << 4;   // read-side swizzle mask

  // DMA chunk coords: chunk = 8 rows x 128 B; lane covers row lane>>3,
  // 16 B at byte (lane&7)*16; source col pre-swizzled by ((row&7)<<4).
  const int crow  = lane >> 3;                              // 0..7
  const int selem = ((((lane & 7) * 16)) ^ (crow << 4)) >> 1;

  float4v acc[MI][2];
#pragma unroll
  for (int i = 0; i < MI; i++)
#pragma unroll
    for (int j = 0; j < 2; j++)
#pragma unroll
      for (int r = 0; r < 4; r++) acc[i][j][r] = 0.f;

#define ISSUE(KK, BUF)                                                         \
  do {                                                                         \
    _Pragma("unroll")                                                          \
    for (int j_ = 0; j_ < NCH / 4; j_++) {                                     \
      const int c_ = wave + j_ * 4;                                            \
      if (c_ < NCHA) {                                                         \
        const int row_ = c_ * 8 + crow;                                        \
        gload16(A + (size_t)(m0 + row_) * K + (KK) + selem,                    \
                (char*)As + (BUF) * ASZ + c_ * 1024);                          \
      } else {                                                                 \
        const int row_ = (c_ - NCHA) * 8 + crow;                               \
        gload16(W + (size_t)(n0 + row_) * K + (KK) + selem,                    \
                (char*)Bs + (BUF) * BSZ + (c_ - NCHA) * 1024);                 \
      }                                                                        \
    }                                                                          \
  } while (0)

  ISSUE(0, 0);
  int cur = 0;

  for (int k0 = 0; k0 < K; k0 += 64) {
    __syncthreads();   // drains DMA (buf cur ready) + prev reads of cur^1 done
    if (k0 + 64 < K) ISSUE(k0 + 64, cur ^ 1);

#pragma unroll
    for (int ks = 0; ks < 2; ks++) {
      short8 af[MI], bfr[2];
#pragma unroll
      for (int i = 0; i < MI; i++)
        af[i] = *(const short8*)((char*)As + cur * ASZ +
                 (wm + i * 16 + l15) * 128 + ((ks * 64 + quad * 16) ^ rmask));
#pragma unroll
      for (int j = 0; j < 2; j++)
        bfr[j] = *(const short8*)((char*)Bs + cur * BSZ +
                 (wn + j * 16 + l15) * 128 + ((ks * 64 + quad * 16) ^ rmask));
#pragma unroll
      for (int i = 0; i < MI; i++)
#pragma unroll
        for (int j = 0; j < 2; j++)
          acc[i][j] = __builtin_amdgcn_mfma_f32_16x16x32_bf16(af[i], bfr[j],
                                                              acc[i][j], 0, 0, 0);
    }
    cur ^= 1;
  }
#undef ISSUE

  if constexpr (MODE == MODE_F1) {
    // deterministic partial: pf[row][ny*2 + (wave&1)] (plain store, no atomics)
    float fsum[MI][4];
#pragma unroll
    for (int i = 0; i < MI; i++)
#pragma unroll
      for (int r = 0; r < 4; r++) fsum[i][r] = 0.f;
#pragma unroll
    for (int j = 0; j < 2; j++) {
      const int col = n0 + wn + j * 16 + l15;
      const float bv = bias[col];
      const float wv = wf2[col];
#pragma unroll
      for (int i = 0; i < MI; i++)
#pragma unroll
        for (int r = 0; r < 4; r++)
          fsum[i][r] += fmaxf(acc[i][j][r] + bv, 0.f) * wv;
    }
#pragma unroll
    for (int i = 0; i < MI; i++)
#pragma unroll
      for (int r = 0; r < 4; r++) {
        float s = fsum[i][r];
        s += __shfl_xor(s, 1, 64); s += __shfl_xor(s, 2, 64);
        s += __shfl_xor(s, 4, 64); s += __shfl_xor(s, 8, 64);
        if (l15 == 0)
          outf[(size_t)(m0 + wm + i * 16 + quad * 4 + r) * 32 +
               blockIdx.y * 2 + (wave & 1)] = s;
      }
  } else {
#pragma unroll
    for (int j = 0; j < 2; j++) {
      const int col = n0 + wn + j * 16 + l15;
      const float bv = bias[col];
#pragma unroll
      for (int i = 0; i < MI; i++) {
#pragma unroll
        for (int r = 0; r < 4; r++) {
          const int row = m0 + wm + i * 16 + quad * 4 + r;
          float v = acc[i][j][r] + bv;
          if constexpr (MODE == MODE_MSG) {
            v = fmaxf(v, 0.f);
            const int dst = edge[E_N + row] & (E_N - 1);  // edge_index[1][row]
            atomicAdd(&aggf[(size_t)dst * H_N + col], v);
          } else if constexpr (MODE == MODE_GI || MODE == MODE_GH) {
            outb[(size_t)row * H3_N + col] = f2bf(v);
          } else if constexpr (MODE == MODE_QKV) {
            const int part = col >> 9;         // 0=q 1=k 2=v
            const int hh   = (col >> 7) & 3;
            const int d    = col & 127;
            // fold 1/sqrt(128) into q so attn needn't scale per-iter
            if (part == 0) v *= 0.088388347648318447f;
            const ushort_t bvv = f2bf(v);
            if (part == 0)      qb[((size_t)hh * E_N + row) * HD_N + d] = bvv;
            else if (part == 1) kb[((size_t)hh * E_N + row) * HD_N + d] = bvv;
            else                vt[((size_t)hh * HD_N + d) * E_N + row] = bvv;  // V^T
          } else if constexpr (MODE == MODE_OUT) {
            v += bf2f(hres[(size_t)row * H_N + col]);   // residual y = o + h
            outf[(size_t)row * H_N + col] = v;
          } else {  // MODE_LIN
            outb[(size_t)row * H_N + col] = f2bf(fmaxf(v, 0.f));
          }
        }
      }
    }
  }
}

// ---------------------------------------------------------------------------
// Flash attention (r8-exact structure; Q pre-scaled so no per-iter scale mul):
// K/V staged via global_load_lds DMA (zero VGPR payload), double-buffered,
// ONE barrier per KV iteration; rule-#21 swizzle; head = bid&3 -> one head
// per XCD (K/V L2-resident).  8 waves; waves 0-3: KV [0,2048), waves 4-7:
// KV [2048,4096); in-LDS flash merge at end.
// ---------------------------------------------------------------------------
__global__ __launch_bounds__(512, 2) void attn_kernel(
    const ushort_t* __restrict__ Qg, const ushort_t* __restrict__ Kg,
    const ushort_t* __restrict__ Vtg, ushort_t* __restrict__ Ob)
{
  const int bid  = blockIdx.x;
  const int head = bid & 3;
  const int qb0  = (bid >> 2) * 64;
  const int tid  = threadIdx.x;
  const int wave = tid >> 6;
  const int grp  = wave >> 2;     // 0/1: which KV half
  const int w4   = wave & 3;      // which 16-row Q sub-tile / staging chunk set
  const int lane = tid & 63;
  const int quad = lane >> 4;
  const int l15  = lane & 15;

  __shared__ ushort_t Ks[2][2][64][128];   // [grp][buf], swizzled, 65536 B
  __shared__ ushort_t Vs[2][2][128][64];   // [grp][buf], swizzled, 65536 B
  __shared__ ushort_t Ps[8][16][64];       // per-wave, swizzled, 16384 B
  char* Psc = (char*)Ps + wave * 2048;

  const ushort_t* Qhead  = Qg  + (size_t)head * E_N * HD_N;
  const ushort_t* Khead  = Kg  + (size_t)head * E_N * HD_N;
  const ushort_t* Vthead = Vtg + (size_t)head * HD_N * E_N;

  // Q A-fragments: loop-invariant, in registers (pre-scaled by 1/sqrt(128)).
  short8 aq[4];
#pragma unroll
  for (int ks = 0; ks < 4; ks++)
    aq[ks] = *(const short8*)(Qhead +
        (size_t)(qb0 + w4 * 16 + l15) * HD_N + ks * 32 + quad * 8);

  float4v oacc[8];
#pragma unroll
  for (int i = 0; i < 8; i++)
#pragma unroll
    for (int r = 0; r < 4; r++) oacc[i][r] = 0.f;
  float mprev[4], lsum[4];
#pragma unroll
  for (int r = 0; r < 4; r++) { mprev[r] = -1e30f; lsum[r] = 0.f; }

  const int q15sw = (l15 & 7) << 4;           // read-side swizzle mask
  const int kt0 = grp * 2048;

#define ISSUE(KT, BUF)                                                         \
  do {                                                                         \
    char* kb_ = (char*)Ks + ((grp * 2 + (BUF)) << 14);                         \
    char* vb_ = (char*)Vs + ((grp * 2 + (BUF)) << 14);                         \
    _Pragma("unroll")                                                          \
    for (int i_ = 0; i_ < 4; i_++) {                                           \
      const int c_ = w4 * 4 + i_;                                              \
      const int krow_ = 4 * c_ + (lane >> 4);      /* tile row 0..63 */        \
      gload16(Khead + (size_t)((KT) + krow_) * HD_N +                          \
                  (((((lane & 15) * 16)) ^ ((krow_ & 7) << 4)) >> 1),          \
              kb_ + c_ * 1024);                                                \
      const int vrow_ = 8 * c_ + (lane >> 3);      /* tile row 0..127 */       \
      gload16(Vthead + (size_t)vrow_ * E_N + (KT) +                            \
                  (((((lane & 7) * 16)) ^ ((lane >> 3) << 4)) >> 1),           \
              vb_ + c_ * 1024);                                                \
    }                                                                          \
  } while (0)

  ISSUE(kt0, 0);   // prologue: tile 0
  int cur = 0;

  for (int it = 0; it < 32; it++) {
    __syncthreads();   // drains DMA (tile it ready) + tile it-1 reads done
    if (it + 1 < 32) ISSUE(kt0 + (it + 1) * 64, cur ^ 1);

    const char* kt_ = (char*)Ks + ((grp * 2 + cur) << 14);
    const char* vt_ = (char*)Vs + ((grp * 2 + cur) << 14);

    float4v sacc[4];
#pragma unroll
    for (int j = 0; j < 4; j++)
#pragma unroll
      for (int r = 0; r < 4; r++) sacc[j][r] = 0.f;
#pragma unroll
    for (int ks = 0; ks < 4; ks++) {
#pragma unroll
      for (int j = 0; j < 4; j++) {
        short8 bk = *(const short8*)(kt_ + (j * 16 + l15) * 256 +
                                     ((ks * 64 + quad * 16) ^ q15sw));
        sacc[j] = __builtin_amdgcn_mfma_f32_16x16x32_bf16(aq[ks], bk, sacc[j], 0, 0, 0);
      }
    }

    float alpha[4], pv[4][4];
#pragma unroll
    for (int r = 0; r < 4; r++) {
      float mx = -1e30f;
#pragma unroll
      for (int j = 0; j < 4; j++) { float s = sacc[j][r]; pv[j][r] = s; mx = fmaxf(mx, s); }
#pragma unroll
      for (int off = 1; off < 16; off <<= 1) mx = fmaxf(mx, __shfl_xor(mx, off, 64));
      float mnew = fmaxf(mprev[r], mx);
      alpha[r] = __expf(mprev[r] - mnew);
      float ss = 0.f;
#pragma unroll
      for (int j = 0; j < 4; j++) { float p = __expf(pv[j][r] - mnew); pv[j][r] = p; ss += p; }
#pragma unroll
      for (int off = 1; off < 16; off <<= 1) ss += __shfl_xor(ss, off, 64);
      lsum[r] = lsum[r] * alpha[r] + ss;
      mprev[r] = mnew;
    }
#pragma unroll
    for (int i = 0; i < 8; i++)
#pragma unroll
      for (int r = 0; r < 4; r++) oacc[i][r] *= alpha[r];

    // Ps write (wave-private, swizzled): within-wave lgkmcnt order, no barrier
#pragma unroll
    for (int j = 0; j < 4; j++)
#pragma unroll
      for (int r = 0; r < 4; r++) {
        const int prow = quad * 4 + r;
        *(ushort_t*)(Psc + prow * 128 +
                     ((2 * (j * 16 + l15)) ^ ((prow & 7) << 4))) = f2bf(pv[j][r]);
      }

#pragma unroll
    for (int ks2 = 0; ks2 < 2; ks2++) {
      short8 ap = *(const short8*)(Psc + l15 * 128 +
                                   ((ks2 * 64 + quad * 16) ^ q15sw));
#pragma unroll
      for (int j = 0; j < 8; j++) {
        short8 bv = *(const short8*)(vt_ + (j * 16 + l15) * 128 +
                                     ((ks2 * 64 + quad * 16) ^ q15sw));
        oacc[j] = __builtin_amdgcn_mfma_f32_16x16x32_bf16(ap, bv, oacc[j], 0, 0, 0);
      }
    }
    cur ^= 1;
  }
#undef ISSUE

  // ---- merge the two KV halves (flash combine), group1 -> LDS -> group0 ----
  __syncthreads();
  float* mO  = (float*)Ks;   // [64][128] fp32 = 32768 B (Ks region is 64 KB)
  float* mML = (float*)Vs;   // [64][2]   fp32
  if (grp == 1) {
#pragma unroll
    for (int j = 0; j < 8; j++)
#pragma unroll
      for (int r = 0; r < 4; r++)
        mO[(w4 * 16 + quad * 4 + r) * 128 + j * 16 + l15] = oacc[j][r];
    if (l15 == 0) {
#pragma unroll
      for (int r = 0; r < 4; r++) {
        mML[(w4 * 16 + quad * 4 + r) * 2 + 0] = mprev[r];
        mML[(w4 * 16 + quad * 4 + r) * 2 + 1] = lsum[r];
      }
    }
  }
  __syncthreads();
  if (grp == 0) {
    float s0[4], s1[4];
#pragma unroll
    for (int r = 0; r < 4; r++) {
      int rr = w4 * 16 + quad * 4 + r;
      float m1 = mML[rr * 2 + 0], l1 = mML[rr * 2 + 1];
      float m  = fmaxf(mprev[r], m1);
      float e0 = __expf(mprev[r] - m);
      float e1 = __expf(m1 - m);
      float inv = 1.f / (lsum[r] * e0 + l1 * e1);
      s0[r] = e0 * inv;
      s1[r] = e1 * inv;
    }
#pragma unroll
    for (int j = 0; j < 8; j++)
#pragma unroll
      for (int r = 0; r < 4; r++) {
        int row = qb0 + w4 * 16 + quad * 4 + r;
        int col = head * HD_N + j * 16 + l15;
        float o1 = mO[(w4 * 16 + quad * 4 + r) * 128 + j * 16 + l15];
        Ob[(size_t)row * H_N + col] = f2bf(oacc[j][r] * s0[r] + o1 * s1[r]);
      }
  }
}

// ---------------------------------------------------------------------------
// GRU elementwise, vectorized: each thread handles 8 contiguous cols.
__global__ __launch_bounds__(256) void gru_kernel(
    const ushort_t* __restrict__ gib, const ushort_t* __restrict__ ghb,
    const float* __restrict__ x, ushort_t* __restrict__ hb) {
  int t = blockIdx.x * 256 + threadIdx.x;         // E*H/8 threads
  int e = t >> 6, j8 = (t & 63) * 8;
  size_t b = (size_t)e * H3_N + j8;
  short8 vir = *(const short8*)(gib + b);
  short8 viz = *(const short8*)(gib + b + 512);
  short8 vin = *(const short8*)(gib + b + 1024);
  short8 vhr = *(const short8*)(ghb + b);
  short8 vhz = *(const short8*)(ghb + b + 512);
  short8 vhn = *(const short8*)(ghb + b + 1024);
  size_t xo = (size_t)e * H_N + j8;
  float4 x0 = *(const float4*)(x + xo);
  float4 x1 = *(const float4*)(x + xo + 4);
  float xv[8] = {x0.x, x0.y, x0.z, x0.w, x1.x, x1.y, x1.z, x1.w};
  union { ushort_t u[8]; uint4 v; } o;
#pragma unroll
  for (int i = 0; i < 8; i++) {
    float ir = bf2f((ushort_t)vir[i]), iz = bf2f((ushort_t)viz[i]), inn = bf2f((ushort_t)vin[i]);
    float hr = bf2f((ushort_t)vhr[i]), hz = bf2f((ushort_t)vhz[i]), hn  = bf2f((ushort_t)vhn[i]);
    float r = 1.f / (1.f + __expf(-(ir + hr)));
    float z = 1.f / (1.f + __expf(-(iz + hz)));
    float n = tanhf(inn + r * hn);
    o.u[i] = f2bf((1.f - z) * n + z * xv[i]);
  }
  *(uint4*)(hb + xo) = o.v;
}

__global__ __launch_bounds__(256) void ln_kernel(
    const float* __restrict__ y, const float* __restrict__ g,
    const float* __restrict__ b, ushort_t* __restrict__ yn) {
  int wave = threadIdx.x >> 6, lane = threadIdx.x & 63;
  int row = blockIdx.x * 4 + wave;
  const float* yr = y + (size_t)row * H_N;
  float v[8], s = 0.f;
#pragma unroll
  for (int i = 0; i < 8; i++) { v[i] = yr[lane + i * 64]; s += v[i]; }
#pragma unroll
  for (int off = 1; off < 64; off <<= 1) s += __shfl_xor(s, off, 64);
  float mu = s * (1.f / 512.f);
  float q = 0.f;
#pragma unroll
  for (int i = 0; i < 8; i++) { float d = v[i] - mu; q += d * d; }
#pragma unroll
  for (int off = 1; off < 64; off <<= 1) q += __shfl_xor(q, off, 64);
  float rstd = rsqrtf(q * (1.f / 512.f) + 1e-5f);
#pragma unroll
  for (int i = 0; i < 8; i++) {
    int c = lane + i * 64;
    yn[(size_t)row * H_N + c] = f2bf((v[i] - mu) * rstd * g[c] + b[c]);
  }
}

// ---------------------------------------------------------------------------
extern "C" void kernel_launch(void* const* d_in, const int* in_sizes, int n_in,
                              void* d_out, int out_size, void* d_ws, size_t ws_size,
                              hipStream_t stream) {
  const float* x     = (const float*)d_in[0];
  const int*   edge  = (const int*)d_in[1];
  const float* W_msg = (const float*)d_in[2];
  const float* b_msg = (const float*)d_in[3];
  const float* W_ih  = (const float*)d_in[4];
  const float* b_ih  = (const float*)d_in[5];
  const float* W_hh  = (const float*)d_in[6];
  const float* b_hh  = (const float*)d_in[7];
  const float* W_in  = (const float*)d_in[8];
  const float* b_in  = (const float*)d_in[9];
  const float* W_out = (const float*)d_in[10];
  const float* b_out = (const float*)d_in[11];
  const float* ln_g  = (const float*)d_in[12];
  const float* ln_b  = (const float*)d_in[13];
  const float* W_lin = (const float*)d_in[14];
  const float* b_lin = (const float*)d_in[15];
  const float* W_f1  = (const float*)d_in[16];
  const float* b_f1  = (const float*)d_in[17];
  const float* W_f2  = (const float*)d_in[18];
  const float* b_f2  = (const float*)d_in[19];

  char* ws = (char*)d_ws;
  const size_t MB = 1024 * 1024;
  // Workspace: r12-exact map (tripwire-proven).  Launch ORDER matters:
  // GI (reads aggb [29,33)) must complete before GH (writes ghb [21,33)).
  float*    agg  = (float*)(ws + 1 * MB);          // [1,9)   prep..cvt_agg
  ushort_t* hb   = (ushort_t*)(ws + 1 * MB);       // [1,5)   gru..OUT (agg dead)
  ushort_t* gib  = (ushort_t*)(ws + 9 * MB);       // [9,21)  bf16 [E][3H], GI..gru
  ushort_t* ghb  = (ushort_t*)(ws + 21 * MB);      // [21,33) bf16 [E][3H], GH..gru
  ushort_t* Qb   = (ushort_t*)(ws + 5 * MB);       // [5,9)   QKV..attn
  ushort_t* Kb   = (ushort_t*)(ws + 9 * MB);       // [9,13)  (gib dead)
  ushort_t* Vt   = (ushort_t*)(ws + 13 * MB);      // [13,17)
  ushort_t* ob   = (ushort_t*)(ws + 17 * MB);      // [17,21) attn..OUT
  float*    y    = (float*)(ws + 21 * MB);         // [21,29) fp32, OUT..ln (ghb dead)
  ushort_t* ynb  = (ushort_t*)(ws + 29 * MB);      // [29,31) ln..LIN
  ushort_t* gb   = (ushort_t*)(ws + 31 * MB);      // [31,33) LIN..F1
  ushort_t* aggb = (ushort_t*)(ws + 29 * MB);      // [29,33) cvt_agg..GI (GH after)
  float*    pf   = (float*)(ws + 21 * MB);         // [21,21.5) F1..f2red (y dead)
  ushort_t* xb   = (ushort_t*)(ws + 33 * MB);      // [33,37) bf16 x
  ushort_t* Wmsg_b = xb + 2097152;                 // weights bf16, contiguous
  ushort_t* Wih_b  = xb + 2359296;
  ushort_t* Whh_b  = xb + 3145728;
  ushort_t* Win_b  = xb + 3932160;
  ushort_t* Wout_b = xb + 4718592;
  ushort_t* Wlin_b = xb + 4980736;
  ushort_t* Wf1_b  = xb + 5242880;

  prep_kernel<<<4864, 256, 0, stream>>>(
      x, W_msg, W_ih, W_hh, W_in, W_out, W_lin, W_f1, xb, (float4*)agg);

  gemm_bt<MODE_MSG, 64><<<dim3(64, 8), 256, 0, stream>>>(
      xb, Wmsg_b, b_msg, H_N, nullptr, nullptr, edge, agg, nullptr,
      nullptr, nullptr, nullptr, nullptr);

  cvt_agg_kernel<<<1024, 256, 0, stream>>>(agg, aggb);

  gemm_bt<MODE_GI, 128><<<dim3(32, 24), 256, 0, stream>>>(
      aggb, Wih_b, b_ih, H_N, nullptr, gib, nullptr, nullptr, nullptr,
      nullptr, nullptr, nullptr, nullptr);

  gemm_bt<MODE_GH, 128><<<dim3(32, 24), 256, 0, stream>>>(
      xb, Whh_b, b_hh, H_N, nullptr, ghb, nullptr, nullptr, nullptr,
      nullptr, nullptr, nullptr, nullptr);

  gru_kernel<<<1024, 256, 0, stream>>>(gib, ghb, x, hb);

  gemm_bt<MODE_QKV, 128><<<dim3(32, 24), 256, 0, stream>>>(
      hb, Win_b, b_in, H_N, nullptr, nullptr, nullptr, nullptr, nullptr,
      Qb, Kb, Vt, nullptr);

  attn_kernel<<<256, 512, 0, stream>>>(Qb, Kb, Vt, ob);

  gemm_bt<MODE_OUT, 64><<<dim3(64, 8), 256, 0, stream>>>(
      ob, Wout_b, b_out, H_N, y, nullptr, nullptr, nullptr, hb,
      nullptr, nullptr, nullptr, nullptr);

  ln_kernel<<<1024, 256, 0, stream>>>(y, ln_g, ln_b, ynb);

  gemm_bt<MODE_LIN, 64><<<dim3(64, 8), 256, 0, stream>>>(
      ynb, Wlin_b, b_lin, H_N, nullptr, gb, nullptr, nullptr, nullptr,
      nullptr, nullptr, nullptr, nullptr);

  gemm_bt<MODE_F1, 64><<<dim3(64, 16), 256, 0, stream>>>(
      gb, Wf1_b, b_f1, H_N, pf, nullptr, nullptr, nullptr, nullptr,
      nullptr, nullptr, nullptr, W_f2);

  f2red_kernel<<<16, 256, 0, stream>>>(pf, b_f2, (float*)d_out);
}

// Round 16
// 285.566 us; speedup vs baseline: 1.0451x; 1.0165x over previous
//
#include <hip/hip_runtime.h>

typedef unsigned short ushort_t;
typedef __attribute__((ext_vector_type(8))) short short8;
typedef __attribute__((ext_vector_type(4))) float float4v;

#define E_N   4096
#define H_N   512
#define NH_N  4
#define HD_N  128
#define FFN_N 1024
#define H3_N  1536

__device__ __forceinline__ float bf2f(ushort_t u) {
  union { unsigned u; float f; } v; v.u = ((unsigned)u) << 16; return v.f;
}
__device__ __forceinline__ ushort_t f2bf(float f) {
  union { float f; unsigned u; } v; v.f = f;
  unsigned r = v.u + 0x7fffu + ((v.u >> 16) & 1u);
  return (ushort_t)(r >> 16);
}
// base-2 exp: bare v_exp_f32 (no log2e premul -- S is pre-scaled to log2 domain)
__device__ __forceinline__ float fexp2(float x) {
  return __builtin_amdgcn_exp2f(x);
}
// 8 consecutive fp32 -> 8 bf16 packed into uint4
__device__ __forceinline__ uint4 cvt8(const float* p) {
  float4 a = *(const float4*)p;
  float4 b = *(const float4*)(p + 4);
  union { ushort_t u[8]; uint4 v; } pk;
  pk.u[0] = f2bf(a.x); pk.u[1] = f2bf(a.y); pk.u[2] = f2bf(a.z); pk.u[3] = f2bf(a.w);
  pk.u[4] = f2bf(b.x); pk.u[5] = f2bf(b.y); pk.u[6] = f2bf(b.z); pk.u[7] = f2bf(b.w);
  return pk.v;
}

// global(16B/lane) -> LDS DMA: no VGPR payload (spill mechanism cannot occur)
__device__ __forceinline__ void gload16(const void* g, void* l) {
  __builtin_amdgcn_global_load_lds(
      (const __attribute__((address_space(1))) unsigned*)g,
      (__attribute__((address_space(3))) unsigned*)l, 16, 0, 0);
}

// ---------------------------------------------------------------------------
// prep: fused {zero agg (blocks 0..2047)} + {fp32->bf16 convert of x + all
// weights (blocks 2048..4863)}.
// ---------------------------------------------------------------------------
__global__ __launch_bounds__(256) void prep_kernel(
    const float* __restrict__ x,
    const float* __restrict__ wmsg, const float* __restrict__ wih,
    const float* __restrict__ whh,  const float* __restrict__ win,
    const float* __restrict__ wout, const float* __restrict__ wlin,
    const float* __restrict__ wf1,  ushort_t* __restrict__ dst,
    float4* __restrict__ agg)
{
  int b = blockIdx.x;
  if (b < 2048) {
    agg[(size_t)b * 256 + threadIdx.x] = make_float4(0.f, 0.f, 0.f, 0.f);
    return;
  }
  size_t o = ((size_t)(b - 2048) * 256 + threadIdx.x) * 8;
  const float* s;
  if      (o < 2097152) s = x    + o;
  else if (o < 2359296) s = wmsg + (o - 2097152);
  else if (o < 3145728) s = wih  + (o - 2359296);
  else if (o < 3932160) s = whh  + (o - 3145728);
  else if (o < 4718592) s = win  + (o - 3932160);
  else if (o < 4980736) s = wout + (o - 4718592);
  else if (o < 5242880) s = wlin + (o - 4980736);
  else                  s = wf1  + (o - 5242880);
  *(uint4*)(dst + o) = cvt8(s);
}

// agg fp32 -> bf16 (runs after MSG's atomics complete)
__global__ __launch_bounds__(256) void cvt_agg_kernel(
    const float* __restrict__ agg, ushort_t* __restrict__ aggb) {
  size_t o = ((size_t)blockIdx.x * 256 + threadIdx.x) * 8;
  *(uint4*)(aggb + o) = cvt8(agg + o);
}

// deterministic F1 reduce: out[row] = b2 + sum_k pf[row][k] (fixed order)
__global__ __launch_bounds__(256) void f2red_kernel(
    const float* __restrict__ pf, const float* __restrict__ b2,
    float* __restrict__ out) {
  int i = blockIdx.x * 256 + threadIdx.x;   // 0..4095
  float s = b2[0];
#pragma unroll
  for (int k = 0; k < 32; k++) s += pf[(size_t)i * 32 + k];
  out[i] = s;
}

// ---------------------------------------------------------------------------
// bf16-MFMA GEMM (DMA-staged): BM x 64 tile, BK=64, 4 waves,
// global_load_lds double-buffer, ONE barrier/iter, rule-#21 swizzle
// (linear LDS dest + pre-swizzled global source, XOR byte^((row&7)<<4)).
// Tile choice is SHAPE-DEPENDENT (r9/r14 A/B): BM=128 for wide GEMMs
// (grid.y=24) and BM=64 for narrow N=512 GEMMs.
// MODE_QKV: q pre-scaled by log2e/sqrt(128) = 0.12751749 so attn softmax
// runs in exp2 domain (bare v_exp_f32, no log2e premul per exp).
// MODE_F1: deterministic partial store (f2red sums in fixed order).
// ---------------------------------------------------------------------------
enum { MODE_MSG = 0, MODE_GI = 1, MODE_GH = 2, MODE_QKV = 3, MODE_OUT = 4,
       MODE_LIN = 5, MODE_F1 = 6 };

template <int MODE, int BM>
__global__ __launch_bounds__(256, (BM == 64 ? 4 : 3)) void gemm_bt(
    const ushort_t* __restrict__ A, const ushort_t* __restrict__ W,
    const float* __restrict__ bias, int K,
    float* __restrict__ outf, ushort_t* __restrict__ outb,
    const int* __restrict__ edge, float* __restrict__ aggf,
    const ushort_t* __restrict__ hres,
    ushort_t* __restrict__ qb, ushort_t* __restrict__ kb,
    ushort_t* __restrict__ vt, const float* __restrict__ wf2)
{
  constexpr int MI   = BM / 32;       // 16-row A fragments per wave
  constexpr int ASZ  = BM * 128;      // bytes per A buffer
  constexpr int BSZ  = 64 * 128;      // bytes per B buffer
  constexpr int NCHA = BM / 8;        // 1024-B A chunks per tile
  constexpr int NCH  = NCHA + 8;      // + 8 B chunks

  __shared__ ushort_t As[2][BM * 64];
  __shared__ ushort_t Bs[2][64 * 64];

  const int tid  = threadIdx.x;
  const int lane = tid & 63;
  const int wave = tid >> 6;
  const int quad = lane >> 4;
  const int l15  = lane & 15;
  const int m0 = blockIdx.x * BM;
  const int n0 = blockIdx.y * 64;
  const int wm = (wave >> 1) * (BM / 2);
  const int wn = (wave & 1) * 32;
  const int rmask = (l15 & 7) << 4;   // read-side swizzle mask

  // DMA chunk coords: chunk = 8 rows x 128 B; lane covers row lane>>3,
  // 16 B at byte (lane&7)*16; source col pre-swizzled by ((row&7)<<4).
  const int crow  = lane >> 3;                              // 0..7
  const int selem = ((((lane & 7) * 16)) ^ (crow << 4)) >> 1;

  float4v acc[MI][2];
#pragma unroll
  for (int i = 0; i < MI; i++)
#pragma unroll
    for (int j = 0; j < 2; j++)
#pragma unroll
      for (int r = 0; r < 4; r++) acc[i][j][r] = 0.f;

#define ISSUE(KK, BUF)                                                         \
  do {                                                                         \
    _Pragma("unroll")                                                          \
    for (int j_ = 0; j_ < NCH / 4; j_++) {                                     \
      const int c_ = wave + j_ * 4;                                            \
      if (c_ < NCHA) {                                                         \
        const int row_ = c_ * 8 + crow;                                        \
        gload16(A + (size_t)(m0 + row_) * K + (KK) + selem,                    \
                (char*)As + (BUF) * ASZ + c_ * 1024);                          \
      } else {                                                                 \
        const int row_ = (c_ - NCHA) * 8 + crow;                               \
        gload16(W + (size_t)(n0 + row_) * K + (KK) + selem,                    \
                (char*)Bs + (BUF) * BSZ + (c_ - NCHA) * 1024);                 \
      }                                                                        \
    }                                                                          \
  } while (0)

  ISSUE(0, 0);
  int cur = 0;

  for (int k0 = 0; k0 < K; k0 += 64) {
    __syncthreads();   // drains DMA (buf cur ready) + prev reads of cur^1 done
    if (k0 + 64 < K) ISSUE(k0 + 64, cur ^ 1);

#pragma unroll
    for (int ks = 0; ks < 2; ks++) {
      short8 af[MI], bfr[2];
#pragma unroll
      for (int i = 0; i < MI; i++)
        af[i] = *(const short8*)((char*)As + cur * ASZ +
                 (wm + i * 16 + l15) * 128 + ((ks * 64 + quad * 16) ^ rmask));
#pragma unroll
      for (int j = 0; j < 2; j++)
        bfr[j] = *(const short8*)((char*)Bs + cur * BSZ +
                 (wn + j * 16 + l15) * 128 + ((ks * 64 + quad * 16) ^ rmask));
#pragma unroll
      for (int i = 0; i < MI; i++)
#pragma unroll
        for (int j = 0; j < 2; j++)
          acc[i][j] = __builtin_amdgcn_mfma_f32_16x16x32_bf16(af[i], bfr[j],
                                                              acc[i][j], 0, 0, 0);
    }
    cur ^= 1;
  }
#undef ISSUE

  if constexpr (MODE == MODE_F1) {
    // deterministic partial: pf[row][ny*2 + (wave&1)] (plain store, no atomics)
    float fsum[MI][4];
#pragma unroll
    for (int i = 0; i < MI; i++)
#pragma unroll
      for (int r = 0; r < 4; r++) fsum[i][r] = 0.f;
#pragma unroll
    for (int j = 0; j < 2; j++) {
      const int col = n0 + wn + j * 16 + l15;
      const float bv = bias[col];
      const float wv = wf2[col];
#pragma unroll
      for (int i = 0; i < MI; i++)
#pragma unroll
        for (int r = 0; r < 4; r++)
          fsum[i][r] += fmaxf(acc[i][j][r] + bv, 0.f) * wv;
    }
#pragma unroll
    for (int i = 0; i < MI; i++)
#pragma unroll
      for (int r = 0; r < 4; r++) {
        float s = fsum[i][r];
        s += __shfl_xor(s, 1, 64); s += __shfl_xor(s, 2, 64);
        s += __shfl_xor(s, 4, 64); s += __shfl_xor(s, 8, 64);
        if (l15 == 0)
          outf[(size_t)(m0 + wm + i * 16 + quad * 4 + r) * 32 +
               blockIdx.y * 2 + (wave & 1)] = s;
      }
  } else {
#pragma unroll
    for (int j = 0; j < 2; j++) {
      const int col = n0 + wn + j * 16 + l15;
      const float bv = bias[col];
#pragma unroll
      for (int i = 0; i < MI; i++) {
#pragma unroll
        for (int r = 0; r < 4; r++) {
          const int row = m0 + wm + i * 16 + quad * 4 + r;
          float v = acc[i][j][r] + bv;
          if constexpr (MODE == MODE_MSG) {
            v = fmaxf(v, 0.f);
            const int dst = edge[E_N + row] & (E_N - 1);  // edge_index[1][row]
            atomicAdd(&aggf[(size_t)dst * H_N + col], v);
          } else if constexpr (MODE == MODE_GI || MODE == MODE_GH) {
            outb[(size_t)row * H3_N + col] = f2bf(v);
          } else if constexpr (MODE == MODE_QKV) {
            const int part = col >> 9;         // 0=q 1=k 2=v
            const int hh   = (col >> 7) & 3;
            const int d    = col & 127;
            // fold log2e/sqrt(128) into q: attn softmax runs in exp2 domain
            if (part == 0) v *= 0.12751749803605814f;
            const ushort_t bvv = f2bf(v);
            if (part == 0)      qb[((size_t)hh * E_N + row) * HD_N + d] = bvv;
            else if (part == 1) kb[((size_t)hh * E_N + row) * HD_N + d] = bvv;
            else                vt[((size_t)hh * HD_N + d) * E_N + row] = bvv;  // V^T
          } else if constexpr (MODE == MODE_OUT) {
            v += bf2f(hres[(size_t)row * H_N + col]);   // residual y = o + h
            outf[(size_t)row * H_N + col] = v;
          } else {  // MODE_LIN
            outb[(size_t)row * H_N + col] = f2bf(fmaxf(v, 0.f));
          }
        }
      }
    }
  }
}

// ---------------------------------------------------------------------------
// Flash attention (r8-exact structure; softmax in exp2 domain -- Q carries
// log2e/sqrt(128), every exp is a bare v_exp_f32; base change is exactly
// softmax-invariant): K/V staged via global_load_lds DMA (zero VGPR
// payload), double-buffered, ONE barrier per KV iteration; rule-#21
// swizzle; head = bid&3 -> one head per XCD (K/V L2-resident).  8 waves;
// waves 0-3: KV [0,2048), waves 4-7: KV [2048,4096); in-LDS flash merge.
// ---------------------------------------------------------------------------
__global__ __launch_bounds__(512, 2) void attn_kernel(
    const ushort_t* __restrict__ Qg, const ushort_t* __restrict__ Kg,
    const ushort_t* __restrict__ Vtg, ushort_t* __restrict__ Ob)
{
  const int bid  = blockIdx.x;
  const int head = bid & 3;
  const int qb0  = (bid >> 2) * 64;
  const int tid  = threadIdx.x;
  const int wave = tid >> 6;
  const int grp  = wave >> 2;     // 0/1: which KV half
  const int w4   = wave & 3;      // which 16-row Q sub-tile / staging chunk set
  const int lane = tid & 63;
  const int quad = lane >> 4;
  const int l15  = lane & 15;

  __shared__ ushort_t Ks[2][2][64][128];   // [grp][buf], swizzled, 65536 B
  __shared__ ushort_t Vs[2][2][128][64];   // [grp][buf], swizzled, 65536 B
  __shared__ ushort_t Ps[8][16][64];       // per-wave, swizzled, 16384 B
  char* Psc = (char*)Ps + wave * 2048;

  const ushort_t* Qhead  = Qg  + (size_t)head * E_N * HD_N;
  const ushort_t* Khead  = Kg  + (size_t)head * E_N * HD_N;
  const ushort_t* Vthead = Vtg + (size_t)head * HD_N * E_N;

  // Q A-fragments: loop-invariant, in registers (pre-scaled, log2 domain).
  short8 aq[4];
#pragma unroll
  for (int ks = 0; ks < 4; ks++)
    aq[ks] = *(const short8*)(Qhead +
        (size_t)(qb0 + w4 * 16 + l15) * HD_N + ks * 32 + quad * 8);

  float4v oacc[8];
#pragma unroll
  for (int i = 0; i < 8; i++)
#pragma unroll
    for (int r = 0; r < 4; r++) oacc[i][r] = 0.f;
  float mprev[4], lsum[4];
#pragma unroll
  for (int r = 0; r < 4; r++) { mprev[r] = -1e30f; lsum[r] = 0.f; }

  const int q15sw = (l15 & 7) << 4;           // read-side swizzle mask
  const int kt0 = grp * 2048;

#define ISSUE(KT, BUF)                                                         \
  do {                                                                         \
    char* kb_ = (char*)Ks + ((grp * 2 + (BUF)) << 14);                         \
    char* vb_ = (char*)Vs + ((grp * 2 + (BUF)) << 14);                         \
    _Pragma("unroll")                                                          \
    for (int i_ = 0; i_ < 4; i_++) {                                           \
      const int c_ = w4 * 4 + i_;                                              \
      const int krow_ = 4 * c_ + (lane >> 4);      /* tile row 0..63 */        \
      gload16(Khead + (size_t)((KT) + krow_) * HD_N +                          \
                  (((((lane & 15) * 16)) ^ ((krow_ & 7) << 4)) >> 1),          \
              kb_ + c_ * 1024);                                                \
      const int vrow_ = 8 * c_ + (lane >> 3);      /* tile row 0..127 */       \
      gload16(Vthead + (size_t)vrow_ * E_N + (KT) +                            \
                  (((((lane & 7) * 16)) ^ ((lane >> 3) << 4)) >> 1),           \
              vb_ + c_ * 1024);                                                \
    }                                                                          \
  } while (0)

  ISSUE(kt0, 0);   // prologue: tile 0
  int cur = 0;

  for (int it = 0; it < 32; it++) {
    __syncthreads();   // drains DMA (tile it ready) + tile it-1 reads done
    if (it + 1 < 32) ISSUE(kt0 + (it + 1) * 64, cur ^ 1);

    const char* kt_ = (char*)Ks + ((grp * 2 + cur) << 14);
    const char* vt_ = (char*)Vs + ((grp * 2 + cur) << 14);

    float4v sacc[4];
#pragma unroll
    for (int j = 0; j < 4; j++)
#pragma unroll
      for (int r = 0; r < 4; r++) sacc[j][r] = 0.f;
#pragma unroll
    for (int ks = 0; ks < 4; ks++) {
#pragma unroll
      for (int j = 0; j < 4; j++) {
        short8 bk = *(const short8*)(kt_ + (j * 16 + l15) * 256 +
                                     ((ks * 64 + quad * 16) ^ q15sw));
        sacc[j] = __builtin_amdgcn_mfma_f32_16x16x32_bf16(aq[ks], bk, sacc[j], 0, 0, 0);
      }
    }

    float alpha[4], pv[4][4];
#pragma unroll
    for (int r = 0; r < 4; r++) {
      float mx = -1e30f;
#pragma unroll
      for (int j = 0; j < 4; j++) { float s = sacc[j][r]; pv[j][r] = s; mx = fmaxf(mx, s); }
#pragma unroll
      for (int off = 1; off < 16; off <<= 1) mx = fmaxf(mx, __shfl_xor(mx, off, 64));
      float mnew = fmaxf(mprev[r], mx);
      alpha[r] = fexp2(mprev[r] - mnew);
      float ss = 0.f;
#pragma unroll
      for (int j = 0; j < 4; j++) { float p = fexp2(pv[j][r] - mnew); pv[j][r] = p; ss += p; }
#pragma unroll
      for (int off = 1; off < 16; off <<= 1) ss += __shfl_xor(ss, off, 64);
      lsum[r] = lsum[r] * alpha[r] + ss;
      mprev[r] = mnew;
    }
#pragma unroll
    for (int i = 0; i < 8; i++)
#pragma unroll
      for (int r = 0; r < 4; r++) oacc[i][r] *= alpha[r];

    // Ps write (wave-private, swizzled): within-wave lgkmcnt order, no barrier
#pragma unroll
    for (int j = 0; j < 4; j++)
#pragma unroll
      for (int r = 0; r < 4; r++) {
        const int prow = quad * 4 + r;
        *(ushort_t*)(Psc + prow * 128 +
                     ((2 * (j * 16 + l15)) ^ ((prow & 7) << 4))) = f2bf(pv[j][r]);
      }

#pragma unroll
    for (int ks2 = 0; ks2 < 2; ks2++) {
      short8 ap = *(const short8*)(Psc + l15 * 128 +
                                   ((ks2 * 64 + quad * 16) ^ q15sw));
#pragma unroll
      for (int j = 0; j < 8; j++) {
        short8 bv = *(const short8*)(vt_ + (j * 16 + l15) * 128 +
                                     ((ks2 * 64 + quad * 16) ^ q15sw));
        oacc[j] = __builtin_amdgcn_mfma_f32_16x16x32_bf16(ap, bv, oacc[j], 0, 0, 0);
      }
    }
    cur ^= 1;
  }
#undef ISSUE

  // ---- merge the two KV halves (flash combine), group1 -> LDS -> group0 ----
  __syncthreads();
  float* mO  = (float*)Ks;   // [64][128] fp32 = 32768 B (Ks region is 64 KB)
  float* mML = (float*)Vs;   // [64][2]   fp32
  if (grp == 1) {
#pragma unroll
    for (int j = 0; j < 8; j++)
#pragma unroll
      for (int r = 0; r < 4; r++)
        mO[(w4 * 16 + quad * 4 + r) * 128 + j * 16 + l15] = oacc[j][r];
    if (l15 == 0) {
#pragma unroll
      for (int r = 0; r < 4; r++) {
        mML[(w4 * 16 + quad * 4 + r) * 2 + 0] = mprev[r];
        mML[(w4 * 16 + quad * 4 + r) * 2 + 1] = lsum[r];
      }
    }
  }
  __syncthreads();
  if (grp == 0) {
    float s0[4], s1[4];
#pragma unroll
    for (int r = 0; r < 4; r++) {
      int rr = w4 * 16 + quad * 4 + r;
      float m1 = mML[rr * 2 + 0], l1 = mML[rr * 2 + 1];
      float m  = fmaxf(mprev[r], m1);
      float e0 = fexp2(mprev[r] - m);
      float e1 = fexp2(m1 - m);
      float inv = 1.f / (lsum[r] * e0 + l1 * e1);
      s0[r] = e0 * inv;
      s1[r] = e1 * inv;
    }
#pragma unroll
    for (int j = 0; j < 8; j++)
#pragma unroll
      for (int r = 0; r < 4; r++) {
        int row = qb0 + w4 * 16 + quad * 4 + r;
        int col = head * HD_N + j * 16 + l15;
        float o1 = mO[(w4 * 16 + quad * 4 + r) * 128 + j * 16 + l15];
        Ob[(size_t)row * H_N + col] = f2bf(oacc[j][r] * s0[r] + o1 * s1[r]);
      }
  }
}

// ---------------------------------------------------------------------------
// GRU elementwise, vectorized: each thread handles 8 contiguous cols.
__global__ __launch_bounds__(256) void gru_kernel(
    const ushort_t* __restrict__ gib, const ushort_t* __restrict__ ghb,
    const float* __restrict__ x, ushort_t* __restrict__ hb) {
  int t = blockIdx.x * 256 + threadIdx.x;         // E*H/8 threads
  int e = t >> 6, j8 = (t & 63) * 8;
  size_t b = (size_t)e * H3_N + j8;
  short8 vir = *(const short8*)(gib + b);
  short8 viz = *(const short8*)(gib + b + 512);
  short8 vin = *(const short8*)(gib + b + 1024);
  short8 vhr = *(const short8*)(ghb + b);
  short8 vhz = *(const short8*)(ghb + b + 512);
  short8 vhn = *(const short8*)(ghb + b + 1024);
  size_t xo = (size_t)e * H_N + j8;
  float4 x0 = *(const float4*)(x + xo);
  float4 x1 = *(const float4*)(x + xo + 4);
  float xv[8] = {x0.x, x0.y, x0.z, x0.w, x1.x, x1.y, x1.z, x1.w};
  union { ushort_t u[8]; uint4 v; } o;
#pragma unroll
  for (int i = 0; i < 8; i++) {
    float ir = bf2f((ushort_t)vir[i]), iz = bf2f((ushort_t)viz[i]), inn = bf2f((ushort_t)vin[i]);
    float hr = bf2f((ushort_t)vhr[i]), hz = bf2f((ushort_t)vhz[i]), hn  = bf2f((ushort_t)vhn[i]);
    float r = 1.f / (1.f + __expf(-(ir + hr)));
    float z = 1.f / (1.f + __expf(-(iz + hz)));
    float n = tanhf(inn + r * hn);
    o.u[i] = f2bf((1.f - z) * n + z * xv[i]);
  }
  *(uint4*)(hb + xo) = o.v;
}

__global__ __launch_bounds__(256) void ln_kernel(
    const float* __restrict__ y, const float* __restrict__ g,
    const float* __restrict__ b, ushort_t* __restrict__ yn) {
  int wave = threadIdx.x >> 6, lane = threadIdx.x & 63;
  int row = blockIdx.x * 4 + wave;
  const float* yr = y + (size_t)row * H_N;
  float v[8], s = 0.f;
#pragma unroll
  for (int i = 0; i < 8; i++) { v[i] = yr[lane + i * 64]; s += v[i]; }
#pragma unroll
  for (int off = 1; off < 64; off <<= 1) s += __shfl_xor(s, off, 64);
  float mu = s * (1.f / 512.f);
  float q = 0.f;
#pragma unroll
  for (int i = 0; i < 8; i++) { float d = v[i] - mu; q += d * d; }
#pragma unroll
  for (int off = 1; off < 64; off <<= 1) q += __shfl_xor(q, off, 64);
  float rstd = rsqrtf(q * (1.f / 512.f) + 1e-5f);
#pragma unroll
  for (int i = 0; i < 8; i++) {
    int c = lane + i * 64;
    yn[(size_t)row * H_N + c] = f2bf((v[i] - mu) * rstd * g[c] + b[c]);
  }
}

// ---------------------------------------------------------------------------
extern "C" void kernel_launch(void* const* d_in, const int* in_sizes, int n_in,
                              void* d_out, int out_size, void* d_ws, size_t ws_size,
                              hipStream_t stream) {
  const float* x     = (const float*)d_in[0];
  const int*   edge  = (const int*)d_in[1];
  const float* W_msg = (const float*)d_in[2];
  const float* b_msg = (const float*)d_in[3];
  const float* W_ih  = (const float*)d_in[4];
  const float* b_ih  = (const float*)d_in[5];
  const float* W_hh  = (const float*)d_in[6];
  const float* b_hh  = (const float*)d_in[7];
  const float* W_in  = (const float*)d_in[8];
  const float* b_in  = (const float*)d_in[9];
  const float* W_out = (const float*)d_in[10];
  const float* b_out = (const float*)d_in[11];
  const float* ln_g  = (const float*)d_in[12];
  const float* ln_b  = (const float*)d_in[13];
  const float* W_lin = (const float*)d_in[14];
  const float* b_lin = (const float*)d_in[15];
  const float* W_f1  = (const float*)d_in[16];
  const float* b_f1  = (const float*)d_in[17];
  const float* W_f2  = (const float*)d_in[18];
  const float* b_f2  = (const float*)d_in[19];

  char* ws = (char*)d_ws;
  const size_t MB = 1024 * 1024;
  // Workspace: r12-exact map (tripwire-proven).  Launch ORDER matters:
  // GI (reads aggb [29,33)) must complete before GH (writes ghb [21,33)).
  float*    agg  = (float*)(ws + 1 * MB);          // [1,9)   prep..cvt_agg
  ushort_t* hb   = (ushort_t*)(ws + 1 * MB);       // [1,5)   gru..OUT (agg dead)
  ushort_t* gib  = (ushort_t*)(ws + 9 * MB);       // [9,21)  bf16 [E][3H], GI..gru
  ushort_t* ghb  = (ushort_t*)(ws + 21 * MB);      // [21,33) bf16 [E][3H], GH..gru
  ushort_t* Qb   = (ushort_t*)(ws + 5 * MB);       // [5,9)   QKV..attn
  ushort_t* Kb   = (ushort_t*)(ws + 9 * MB);       // [9,13)  (gib dead)
  ushort_t* Vt   = (ushort_t*)(ws + 13 * MB);      // [13,17)
  ushort_t* ob   = (ushort_t*)(ws + 17 * MB);      // [17,21) attn..OUT
  float*    y    = (float*)(ws + 21 * MB);         // [21,29) fp32, OUT..ln (ghb dead)
  ushort_t* ynb  = (ushort_t*)(ws + 29 * MB);      // [29,31) ln..LIN
  ushort_t* gb   = (ushort_t*)(ws + 31 * MB);      // [31,33) LIN..F1
  ushort_t* aggb = (ushort_t*)(ws + 29 * MB);      // [29,33) cvt_agg..GI (GH after)
  float*    pf   = (float*)(ws + 21 * MB);         // [21,21.5) F1..f2red (y dead)
  ushort_t* xb   = (ushort_t*)(ws + 33 * MB);      // [33,37) bf16 x
  ushort_t* Wmsg_b = xb + 2097152;                 // weights bf16, contiguous
  ushort_t* Wih_b  = xb + 2359296;
  ushort_t* Whh_b  = xb + 3145728;
  ushort_t* Win_b  = xb + 3932160;
  ushort_t* Wout_b = xb + 4718592;
  ushort_t* Wlin_b = xb + 4980736;
  ushort_t* Wf1_b  = xb + 5242880;

  prep_kernel<<<4864, 256, 0, stream>>>(
      x, W_msg, W_ih, W_hh, W_in, W_out, W_lin, W_f1, xb, (float4*)agg);

  gemm_bt<MODE_MSG, 64><<<dim3(64, 8), 256, 0, stream>>>(
      xb, Wmsg_b, b_msg, H_N, nullptr, nullptr, edge, agg, nullptr,
      nullptr, nullptr, nullptr, nullptr);

  cvt_agg_kernel<<<1024, 256, 0, stream>>>(agg, aggb);

  gemm_bt<MODE_GI, 128><<<dim3(32, 24), 256, 0, stream>>>(
      aggb, Wih_b, b_ih, H_N, nullptr, gib, nullptr, nullptr, nullptr,
      nullptr, nullptr, nullptr, nullptr);

  gemm_bt<MODE_GH, 128><<<dim3(32, 24), 256, 0, stream>>>(
      xb, Whh_b, b_hh, H_N, nullptr, ghb, nullptr, nullptr, nullptr,
      nullptr, nullptr, nullptr, nullptr);

  gru_kernel<<<1024, 256, 0, stream>>>(gib, ghb, x, hb);

  gemm_bt<MODE_QKV, 128><<<dim3(32, 24), 256, 0, stream>>>(
      hb, Win_b, b_in, H_N, nullptr, nullptr, nullptr, nullptr, nullptr,
      Qb, Kb, Vt, nullptr);

  attn_kernel<<<256, 512, 0, stream>>>(Qb, Kb, Vt, ob);

  gemm_bt<MODE_OUT, 64><<<dim3(64, 8), 256, 0, stream>>>(
      ob, Wout_b, b_out, H_N, y, nullptr, nullptr, nullptr, hb,
      nullptr, nullptr, nullptr, nullptr);

  ln_kernel<<<1024, 256, 0, stream>>>(y, ln_g, ln_b, ynb);

  gemm_bt<MODE_LIN, 64><<<dim3(64, 8), 256, 0, stream>>>(
      ynb, Wlin_b, b_lin, H_N, nullptr, gb, nullptr, nullptr, nullptr,
      nullptr, nullptr, nullptr, nullptr);

  gemm_bt<MODE_F1, 64><<<dim3(64, 16), 256, 0, stream>>>(
      gb, Wf1_b, b_f1, H_N, pf, nullptr, nullptr, nullptr, nullptr,
      nullptr, nullptr, nullptr, W_f2);

  f2red_kernel<<<16, 256, 0, stream>>>(pf, b_f2, (float*)d_out);
}

// Round 17
// 284.590 us; speedup vs baseline: 1.0487x; 1.0034x over previous
//
#include <hip/hip_runtime.h>

typedef unsigned short ushort_t;
typedef __attribute__((ext_vector_type(8))) short short8;
typedef __attribute__((ext_vector_type(4))) float float4v;

#define E_N   4096
#define H_N   512
#define NH_N  4
#define HD_N  128
#define FFN_N 1024
#define H3_N  1536

__device__ __forceinline__ float bf2f(ushort_t u) {
  union { unsigned u; float f; } v; v.u = ((unsigned)u) << 16; return v.f;
}
__device__ __forceinline__ ushort_t f2bf(float f) {
  union { float f; unsigned u; } v; v.f = f;
  unsigned r = v.u + 0x7fffu + ((v.u >> 16) & 1u);
  return (ushort_t)(r >> 16);
}
// base-2 exp: bare v_exp_f32 (S pre-scaled to log2 domain via QKV epilogue)
__device__ __forceinline__ float fexp2(float x) {
  return __builtin_amdgcn_exp2f(x);
}
// 8 consecutive fp32 -> 8 bf16 packed into uint4
__device__ __forceinline__ uint4 cvt8(const float* p) {
  float4 a = *(const float4*)p;
  float4 b = *(const float4*)(p + 4);
  union { ushort_t u[8]; uint4 v; } pk;
  pk.u[0] = f2bf(a.x); pk.u[1] = f2bf(a.y); pk.u[2] = f2bf(a.z); pk.u[3] = f2bf(a.w);
  pk.u[4] = f2bf(b.x); pk.u[5] = f2bf(b.y); pk.u[6] = f2bf(b.z); pk.u[7] = f2bf(b.w);
  return pk.v;
}

// global(16B/lane) -> LDS DMA: no VGPR payload (spill mechanism cannot occur)
__device__ __forceinline__ void gload16(const void* g, void* l) {
  __builtin_amdgcn_global_load_lds(
      (const __attribute__((address_space(1))) unsigned*)g,
      (__attribute__((address_space(3))) unsigned*)l, 16, 0, 0);
}

// ---------------------------------------------------------------------------
// prep: fused {zero agg (blocks 0..2047)} + {fp32->bf16 convert of x + all
// weights (blocks 2048..4863)}.
// ---------------------------------------------------------------------------
__global__ __launch_bounds__(256) void prep_kernel(
    const float* __restrict__ x,
    const float* __restrict__ wmsg, const float* __restrict__ wih,
    const float* __restrict__ whh,  const float* __restrict__ win,
    const float* __restrict__ wout, const float* __restrict__ wlin,
    const float* __restrict__ wf1,  ushort_t* __restrict__ dst,
    float4* __restrict__ agg)
{
  int b = blockIdx.x;
  if (b < 2048) {
    agg[(size_t)b * 256 + threadIdx.x] = make_float4(0.f, 0.f, 0.f, 0.f);
    return;
  }
  size_t o = ((size_t)(b - 2048) * 256 + threadIdx.x) * 8;
  const float* s;
  if      (o < 2097152) s = x    + o;
  else if (o < 2359296) s = wmsg + (o - 2097152);
  else if (o < 3145728) s = wih  + (o - 2359296);
  else if (o < 3932160) s = whh  + (o - 3145728);
  else if (o < 4718592) s = win  + (o - 3932160);
  else if (o < 4980736) s = wout + (o - 4718592);
  else if (o < 5242880) s = wlin + (o - 4980736);
  else                  s = wf1  + (o - 5242880);
  *(uint4*)(dst + o) = cvt8(s);
}

// agg fp32 -> bf16 (runs after MSG's atomics complete)
__global__ __launch_bounds__(256) void cvt_agg_kernel(
    const float* __restrict__ agg, ushort_t* __restrict__ aggb) {
  size_t o = ((size_t)blockIdx.x * 256 + threadIdx.x) * 8;
  *(uint4*)(aggb + o) = cvt8(agg + o);
}

// deterministic F1 reduce: out[row] = b2 + sum_k pf[row][k] (fixed order)
__global__ __launch_bounds__(256) void f2red_kernel(
    const float* __restrict__ pf, const float* __restrict__ b2,
    float* __restrict__ out) {
  int i = blockIdx.x * 256 + threadIdx.x;   // 0..4095
  float s = b2[0];
#pragma unroll
  for (int k = 0; k < 32; k++) s += pf[(size_t)i * 32 + k];
  out[i] = s;
}

// ---------------------------------------------------------------------------
// attn flash-merge: combine the two unnormalized KV-half partials (fp32,
// exact same math as the old in-LDS merge; fixed order -> deterministic).
// ---------------------------------------------------------------------------
__global__ __launch_bounds__(256) void amerge_kernel(
    const float* __restrict__ po0, const float* __restrict__ po1,
    const float* __restrict__ mlg, ushort_t* __restrict__ ob) {
  int t = blockIdx.x * 256 + threadIdx.x;       // E*H/8 threads
  int row = t >> 6;
  int c8  = (t & 63) * 8;
  int head = c8 >> 7;
  const float* p0 = mlg + ((size_t)(0 * 4 + head) * E_N + row) * 2;
  const float* p1 = mlg + ((size_t)(1 * 4 + head) * E_N + row) * 2;
  float m0 = p0[0], l0 = p0[1], m1 = p1[0], l1 = p1[1];
  float m  = fmaxf(m0, m1);
  float e0 = fexp2(m0 - m), e1 = fexp2(m1 - m);
  float inv = 1.f / (l0 * e0 + l1 * e1);
  float s0 = e0 * inv, s1 = e1 * inv;
  size_t off = (size_t)row * H_N + c8;
  float4 a0 = *(const float4*)(po0 + off);
  float4 a1 = *(const float4*)(po0 + off + 4);
  float4 b0 = *(const float4*)(po1 + off);
  float4 b1 = *(const float4*)(po1 + off + 4);
  union { ushort_t u[8]; uint4 v; } o;
  o.u[0] = f2bf(a0.x * s0 + b0.x * s1); o.u[1] = f2bf(a0.y * s0 + b0.y * s1);
  o.u[2] = f2bf(a0.z * s0 + b0.z * s1); o.u[3] = f2bf(a0.w * s0 + b0.w * s1);
  o.u[4] = f2bf(a1.x * s0 + b1.x * s1); o.u[5] = f2bf(a1.y * s0 + b1.y * s1);
  o.u[6] = f2bf(a1.z * s0 + b1.z * s1); o.u[7] = f2bf(a1.w * s0 + b1.w * s1);
  *(uint4*)(ob + off) = o.v;
}

// ---------------------------------------------------------------------------
// bf16-MFMA GEMM (DMA-staged): BM x 64 tile, BK=64, 4 waves,
// global_load_lds double-buffer, ONE barrier/iter, rule-#21 swizzle.
// BM=128 for wide GEMMs (grid.y=24), BM=64 for narrow N=512 GEMMs.
// MODE_QKV: q pre-scaled by log2e/sqrt(128) (exp2-domain softmax).
// MODE_F1: deterministic partial store (f2red sums in fixed order).
// ---------------------------------------------------------------------------
enum { MODE_MSG = 0, MODE_GI = 1, MODE_GH = 2, MODE_QKV = 3, MODE_OUT = 4,
       MODE_LIN = 5, MODE_F1 = 6 };

template <int MODE, int BM>
__global__ __launch_bounds__(256, (BM == 64 ? 4 : 3)) void gemm_bt(
    const ushort_t* __restrict__ A, const ushort_t* __restrict__ W,
    const float* __restrict__ bias, int K,
    float* __restrict__ outf, ushort_t* __restrict__ outb,
    const int* __restrict__ edge, float* __restrict__ aggf,
    const ushort_t* __restrict__ hres,
    ushort_t* __restrict__ qb, ushort_t* __restrict__ kb,
    ushort_t* __restrict__ vt, const float* __restrict__ wf2)
{
  constexpr int MI   = BM / 32;
  constexpr int ASZ  = BM * 128;
  constexpr int BSZ  = 64 * 128;
  constexpr int NCHA = BM / 8;
  constexpr int NCH  = NCHA + 8;

  __shared__ ushort_t As[2][BM * 64];
  __shared__ ushort_t Bs[2][64 * 64];

  const int tid  = threadIdx.x;
  const int lane = tid & 63;
  const int wave = tid >> 6;
  const int quad = lane >> 4;
  const int l15  = lane & 15;
  const int m0 = blockIdx.x * BM;
  const int n0 = blockIdx.y * 64;
  const int wm = (wave >> 1) * (BM / 2);
  const int wn = (wave & 1) * 32;
  const int rmask = (l15 & 7) << 4;

  const int crow  = lane >> 3;
  const int selem = ((((lane & 7) * 16)) ^ (crow << 4)) >> 1;

  float4v acc[MI][2];
#pragma unroll
  for (int i = 0; i < MI; i++)
#pragma unroll
    for (int j = 0; j < 2; j++)
#pragma unroll
      for (int r = 0; r < 4; r++) acc[i][j][r] = 0.f;

#define ISSUE(KK, BUF)                                                         \
  do {                                                                         \
    _Pragma("unroll")                                                          \
    for (int j_ = 0; j_ < NCH / 4; j_++) {                                     \
      const int c_ = wave + j_ * 4;                                            \
      if (c_ < NCHA) {                                                         \
        const int row_ = c_ * 8 + crow;                                        \
        gload16(A + (size_t)(m0 + row_) * K + (KK) + selem,                    \
                (char*)As + (BUF) * ASZ + c_ * 1024);                          \
      } else {                                                                 \
        const int row_ = (c_ - NCHA) * 8 + crow;                               \
        gload16(W + (size_t)(n0 + row_) * K + (KK) + selem,                    \
                (char*)Bs + (BUF) * BSZ + (c_ - NCHA) * 1024);                 \
      }                                                                        \
    }                                                                          \
  } while (0)

  ISSUE(0, 0);
  int cur = 0;

  for (int k0 = 0; k0 < K; k0 += 64) {
    __syncthreads();
    if (k0 + 64 < K) ISSUE(k0 + 64, cur ^ 1);

#pragma unroll
    for (int ks = 0; ks < 2; ks++) {
      short8 af[MI], bfr[2];
#pragma unroll
      for (int i = 0; i < MI; i++)
        af[i] = *(const short8*)((char*)As + cur * ASZ +
                 (wm + i * 16 + l15) * 128 + ((ks * 64 + quad * 16) ^ rmask));
#pragma unroll
      for (int j = 0; j < 2; j++)
        bfr[j] = *(const short8*)((char*)Bs + cur * BSZ +
                 (wn + j * 16 + l15) * 128 + ((ks * 64 + quad * 16) ^ rmask));
#pragma unroll
      for (int i = 0; i < MI; i++)
#pragma unroll
        for (int j = 0; j < 2; j++)
          acc[i][j] = __builtin_amdgcn_mfma_f32_16x16x32_bf16(af[i], bfr[j],
                                                              acc[i][j], 0, 0, 0);
    }
    cur ^= 1;
  }
#undef ISSUE

  if constexpr (MODE == MODE_F1) {
    float fsum[MI][4];
#pragma unroll
    for (int i = 0; i < MI; i++)
#pragma unroll
      for (int r = 0; r < 4; r++) fsum[i][r] = 0.f;
#pragma unroll
    for (int j = 0; j < 2; j++) {
      const int col = n0 + wn + j * 16 + l15;
      const float bv = bias[col];
      const float wv = wf2[col];
#pragma unroll
      for (int i = 0; i < MI; i++)
#pragma unroll
        for (int r = 0; r < 4; r++)
          fsum[i][r] += fmaxf(acc[i][j][r] + bv, 0.f) * wv;
    }
#pragma unroll
    for (int i = 0; i < MI; i++)
#pragma unroll
      for (int r = 0; r < 4; r++) {
        float s = fsum[i][r];
        s += __shfl_xor(s, 1, 64); s += __shfl_xor(s, 2, 64);
        s += __shfl_xor(s, 4, 64); s += __shfl_xor(s, 8, 64);
        if (l15 == 0)
          outf[(size_t)(m0 + wm + i * 16 + quad * 4 + r) * 32 +
               blockIdx.y * 2 + (wave & 1)] = s;
      }
  } else {
#pragma unroll
    for (int j = 0; j < 2; j++) {
      const int col = n0 + wn + j * 16 + l15;
      const float bv = bias[col];
#pragma unroll
      for (int i = 0; i < MI; i++) {
#pragma unroll
        for (int r = 0; r < 4; r++) {
          const int row = m0 + wm + i * 16 + quad * 4 + r;
          float v = acc[i][j][r] + bv;
          if constexpr (MODE == MODE_MSG) {
            v = fmaxf(v, 0.f);
            const int dst = edge[E_N + row] & (E_N - 1);  // edge_index[1][row]
            atomicAdd(&aggf[(size_t)dst * H_N + col], v);
          } else if constexpr (MODE == MODE_GI || MODE == MODE_GH) {
            outb[(size_t)row * H3_N + col] = f2bf(v);
          } else if constexpr (MODE == MODE_QKV) {
            const int part = col >> 9;         // 0=q 1=k 2=v
            const int hh   = (col >> 7) & 3;
            const int d    = col & 127;
            // fold log2e/sqrt(128) into q: attn softmax runs in exp2 domain
            if (part == 0) v *= 0.12751749803605814f;
            const ushort_t bvv = f2bf(v);
            if (part == 0)      qb[((size_t)hh * E_N + row) * HD_N + d] = bvv;
            else if (part == 1) kb[((size_t)hh * E_N + row) * HD_N + d] = bvv;
            else                vt[((size_t)hh * HD_N + d) * E_N + row] = bvv;  // V^T
          } else if constexpr (MODE == MODE_OUT) {
            v += bf2f(hres[(size_t)row * H_N + col]);   // residual y = o + h
            outf[(size_t)row * H_N + col] = v;
          } else {  // MODE_LIN
            outb[(size_t)row * H_N + col] = f2bf(fmaxf(v, 0.f));
          }
        }
      }
    }
  }
}

// ---------------------------------------------------------------------------
// Flash attention v10: 512 INDEPENDENT 4-wave blocks (one per {q-tile, head,
// KV-half}), 72 KB LDS -> 2 blocks/CU.  Rationale (r16 plateau analysis):
// the 8-wave 147 KB block was 1 block/CU with every wave coupled to one
// barrier -- DMA-drain stalls idled the whole CU.  Now when one block waits,
// the co-resident block's waves keep issuing MFMA.  Same DMA staging,
// swizzle, exp2 softmax per wave.  Blocks write UNNORMALIZED fp32 partial O
// + (m,l); amerge combines (same math as old in-LDS merge, zero added
// rounding, fixed order).  bid&3 = head keeps the per-XCD L2 mapping.
// ---------------------------------------------------------------------------
__global__ __launch_bounds__(256, 2) void attn_kernel(
    const ushort_t* __restrict__ Qg, const ushort_t* __restrict__ Kg,
    const ushort_t* __restrict__ Vtg,
    float* __restrict__ po0, float* __restrict__ po1,
    float* __restrict__ mlg)
{
  const int bid  = blockIdx.x;
  const int head = bid & 3;
  const int half = (bid >> 2) & 1;
  const int qb0  = (bid >> 3) * 64;
  const int tid  = threadIdx.x;
  const int wave = tid >> 6;      // 0..3: Q sub-tile + staging chunk set
  const int lane = tid & 63;
  const int quad = lane >> 4;
  const int l15  = lane & 15;

  __shared__ ushort_t Ks[2][64][128];   // dbuf, swizzled, 32768 B
  __shared__ ushort_t Vs[2][128][64];   // dbuf, swizzled, 32768 B
  __shared__ ushort_t Ps[4][16][64];    // per-wave, swizzled, 8192 B
  char* Psc = (char*)Ps + wave * 2048;

  const ushort_t* Qhead  = Qg  + (size_t)head * E_N * HD_N;
  const ushort_t* Khead  = Kg  + (size_t)head * E_N * HD_N;
  const ushort_t* Vthead = Vtg + (size_t)head * HD_N * E_N;

  // Q A-fragments: loop-invariant, in registers (pre-scaled, log2 domain).
  short8 aq[4];
#pragma unroll
  for (int ks = 0; ks < 4; ks++)
    aq[ks] = *(const short8*)(Qhead +
        (size_t)(qb0 + wave * 16 + l15) * HD_N + ks * 32 + quad * 8);

  float4v oacc[8];
#pragma unroll
  for (int i = 0; i < 8; i++)
#pragma unroll
    for (int r = 0; r < 4; r++) oacc[i][r] = 0.f;
  float mprev[4], lsum[4];
#pragma unroll
  for (int r = 0; r < 4; r++) { mprev[r] = -1e30f; lsum[r] = 0.f; }

  const int q15sw = (l15 & 7) << 4;           // read-side swizzle mask
  const int kt0 = half * 2048;

#define ISSUE(KT, BUF)                                                         \
  do {                                                                         \
    char* kb_ = (char*)Ks + ((BUF) << 14);                                     \
    char* vb_ = (char*)Vs + ((BUF) << 14);                                     \
    _Pragma("unroll")                                                          \
    for (int i_ = 0; i_ < 4; i_++) {                                           \
      const int c_ = wave * 4 + i_;                                            \
      const int krow_ = 4 * c_ + (lane >> 4);      /* tile row 0..63 */        \
      gload16(Khead + (size_t)((KT) + krow_) * HD_N +                          \
                  (((((lane & 15) * 16)) ^ ((krow_ & 7) << 4)) >> 1),          \
              kb_ + c_ * 1024);                                                \
      const int vrow_ = 8 * c_ + (lane >> 3);      /* tile row 0..127 */       \
      gload16(Vthead + (size_t)vrow_ * E_N + (KT) +                            \
                  (((((lane & 7) * 16)) ^ ((lane >> 3) << 4)) >> 1),           \
              vb_ + c_ * 1024);                                                \
    }                                                                          \
  } while (0)

  ISSUE(kt0, 0);   // prologue: tile 0
  int cur = 0;

  for (int it = 0; it < 32; it++) {
    __syncthreads();   // drains DMA (tile it ready) + tile it-1 reads done
    if (it + 1 < 32) ISSUE(kt0 + (it + 1) * 64, cur ^ 1);

    const char* kt_ = (char*)Ks + (cur << 14);
    const char* vt_ = (char*)Vs + (cur << 14);

    float4v sacc[4];
#pragma unroll
    for (int j = 0; j < 4; j++)
#pragma unroll
      for (int r = 0; r < 4; r++) sacc[j][r] = 0.f;
#pragma unroll
    for (int ks = 0; ks < 4; ks++) {
#pragma unroll
      for (int j = 0; j < 4; j++) {
        short8 bk = *(const short8*)(kt_ + (j * 16 + l15) * 256 +
                                     ((ks * 64 + quad * 16) ^ q15sw));
        sacc[j] = __builtin_amdgcn_mfma_f32_16x16x32_bf16(aq[ks], bk, sacc[j], 0, 0, 0);
      }
    }

    float alpha[4], pv[4][4];
#pragma unroll
    for (int r = 0; r < 4; r++) {
      float mx = -1e30f;
#pragma unroll
      for (int j = 0; j < 4; j++) { float s = sacc[j][r]; pv[j][r] = s; mx = fmaxf(mx, s); }
#pragma unroll
      for (int off = 1; off < 16; off <<= 1) mx = fmaxf(mx, __shfl_xor(mx, off, 64));
      float mnew = fmaxf(mprev[r], mx);
      alpha[r] = fexp2(mprev[r] - mnew);
      float ss = 0.f;
#pragma unroll
      for (int j = 0; j < 4; j++) { float p = fexp2(pv[j][r] - mnew); pv[j][r] = p; ss += p; }
#pragma unroll
      for (int off = 1; off < 16; off <<= 1) ss += __shfl_xor(ss, off, 64);
      lsum[r] = lsum[r] * alpha[r] + ss;
      mprev[r] = mnew;
    }
#pragma unroll
    for (int i = 0; i < 8; i++)
#pragma unroll
      for (int r = 0; r < 4; r++) oacc[i][r] *= alpha[r];

    // Ps write (wave-private, swizzled): within-wave lgkmcnt order, no barrier
#pragma unroll
    for (int j = 0; j < 4; j++)
#pragma unroll
      for (int r = 0; r < 4; r++) {
        const int prow = quad * 4 + r;
        *(ushort_t*)(Psc + prow * 128 +
                     ((2 * (j * 16 + l15)) ^ ((prow & 7) << 4))) = f2bf(pv[j][r]);
      }

#pragma unroll
    for (int ks2 = 0; ks2 < 2; ks2++) {
      short8 ap = *(const short8*)(Psc + l15 * 128 +
                                   ((ks2 * 64 + quad * 16) ^ q15sw));
#pragma unroll
      for (int j = 0; j < 8; j++) {
        short8 bv = *(const short8*)(vt_ + (j * 16 + l15) * 128 +
                                     ((ks2 * 64 + quad * 16) ^ q15sw));
        oacc[j] = __builtin_amdgcn_mfma_f32_16x16x32_bf16(ap, bv, oacc[j], 0, 0, 0);
      }
    }
    cur ^= 1;
  }
#undef ISSUE

  // ---- epilogue: unnormalized fp32 partial O + (m,l) to workspace ----
  float* pob = half ? po1 : po0;
#pragma unroll
  for (int j = 0; j < 8; j++)
#pragma unroll
    for (int r = 0; r < 4; r++) {
      const int row = qb0 + wave * 16 + quad * 4 + r;
      const int col = head * HD_N + j * 16 + l15;
      pob[(size_t)row * H_N + col] = oacc[j][r];
    }
  if (l15 == 0) {
#pragma unroll
    for (int r = 0; r < 4; r++) {
      const int row = qb0 + wave * 16 + quad * 4 + r;
      float* mlp = mlg + ((size_t)(half * 4 + head) * E_N + row) * 2;
      mlp[0] = mprev[r];
      mlp[1] = lsum[r];
    }
  }
}

// ---------------------------------------------------------------------------
// GRU elementwise, vectorized: each thread handles 8 contiguous cols.
__global__ __launch_bounds__(256) void gru_kernel(
    const ushort_t* __restrict__ gib, const ushort_t* __restrict__ ghb,
    const float* __restrict__ x, ushort_t* __restrict__ hb) {
  int t = blockIdx.x * 256 + threadIdx.x;         // E*H/8 threads
  int e = t >> 6, j8 = (t & 63) * 8;
  size_t b = (size_t)e * H3_N + j8;
  short8 vir = *(const short8*)(gib + b);
  short8 viz = *(const short8*)(gib + b + 512);
  short8 vin = *(const short8*)(gib + b + 1024);
  short8 vhr = *(const short8*)(ghb + b);
  short8 vhz = *(const short8*)(ghb + b + 512);
  short8 vhn = *(const short8*)(ghb + b + 1024);
  size_t xo = (size_t)e * H_N + j8;
  float4 x0 = *(const float4*)(x + xo);
  float4 x1 = *(const float4*)(x + xo + 4);
  float xv[8] = {x0.x, x0.y, x0.z, x0.w, x1.x, x1.y, x1.z, x1.w};
  union { ushort_t u[8]; uint4 v; } o;
#pragma unroll
  for (int i = 0; i < 8; i++) {
    float ir = bf2f((ushort_t)vir[i]), iz = bf2f((ushort_t)viz[i]), inn = bf2f((ushort_t)vin[i]);
    float hr = bf2f((ushort_t)vhr[i]), hz = bf2f((ushort_t)vhz[i]), hn  = bf2f((ushort_t)vhn[i]);
    float r = 1.f / (1.f + __expf(-(ir + hr)));
    float z = 1.f / (1.f + __expf(-(iz + hz)));
    float n = tanhf(inn + r * hn);
    o.u[i] = f2bf((1.f - z) * n + z * xv[i]);
  }
  *(uint4*)(hb + xo) = o.v;
}

__global__ __launch_bounds__(256) void ln_kernel(
    const float* __restrict__ y, const float* __restrict__ g,
    const float* __restrict__ b, ushort_t* __restrict__ yn) {
  int wave = threadIdx.x >> 6, lane = threadIdx.x & 63;
  int row = blockIdx.x * 4 + wave;
  const float* yr = y + (size_t)row * H_N;
  float v[8], s = 0.f;
#pragma unroll
  for (int i = 0; i < 8; i++) { v[i] = yr[lane + i * 64]; s += v[i]; }
#pragma unroll
  for (int off = 1; off < 64; off <<= 1) s += __shfl_xor(s, off, 64);
  float mu = s * (1.f / 512.f);
  float q = 0.f;
#pragma unroll
  for (int i = 0; i < 8; i++) { float d = v[i] - mu; q += d * d; }
#pragma unroll
  for (int off = 1; off < 64; off <<= 1) q += __shfl_xor(q, off, 64);
  float rstd = rsqrtf(q * (1.f / 512.f) + 1e-5f);
#pragma unroll
  for (int i = 0; i < 8; i++) {
    int c = lane + i * 64;
    yn[(size_t)row * H_N + c] = f2bf((v[i] - mu) * rstd * g[c] + b[c]);
  }
}

// ---------------------------------------------------------------------------
extern "C" void kernel_launch(void* const* d_in, const int* in_sizes, int n_in,
                              void* d_out, int out_size, void* d_ws, size_t ws_size,
                              hipStream_t stream) {
  const float* x     = (const float*)d_in[0];
  const int*   edge  = (const int*)d_in[1];
  const float* W_msg = (const float*)d_in[2];
  const float* b_msg = (const float*)d_in[3];
  const float* W_ih  = (const float*)d_in[4];
  const float* b_ih  = (const float*)d_in[5];
  const float* W_hh  = (const float*)d_in[6];
  const float* b_hh  = (const float*)d_in[7];
  const float* W_in  = (const float*)d_in[8];
  const float* b_in  = (const float*)d_in[9];
  const float* W_out = (const float*)d_in[10];
  const float* b_out = (const float*)d_in[11];
  const float* ln_g  = (const float*)d_in[12];
  const float* ln_b  = (const float*)d_in[13];
  const float* W_lin = (const float*)d_in[14];
  const float* b_lin = (const float*)d_in[15];
  const float* W_f1  = (const float*)d_in[16];
  const float* b_f1  = (const float*)d_in[17];
  const float* W_f2  = (const float*)d_in[18];
  const float* b_f2  = (const float*)d_in[19];

  char* ws = (char*)d_ws;
  const size_t MB = 1024 * 1024;
  // Workspace (liveness-audited for the split attn):
  //  [1,9)    agg (prep..cvt_agg)           | hb [1,5) gru..OUT (agg dead)
  //  [5,9)    Qb  QKV..attn
  //  [9,13)   Kb  QKV..attn   (gib [9,21) dead after gru)
  //  [13,17)  Vt  QKV..attn
  //  [17,21)  ob  amerge..OUT
  //  [21,29)  po0 attn..amerge  -> then y OUT..ln (po0 dead)
  //  [29,33)  aggb cvt_agg..GI; GH writes ghb [21,33) AFTER GI; ghb dead
  //           after gru; ynb [29,31) ln..LIN; gb [31,33) LIN..F1
  //  [33,41)  po1 attn..amerge (xb + Wmsg..Win bf16, all dead after QKV;
  //           Wout_b starts at byte 33MB+9MB=42MB -- no overlap)
  //  [41,41.25) mlg attn..amerge
  //  [21,21.5) pf F1..f2red (y dead after ln)
  float*    agg  = (float*)(ws + 1 * MB);
  ushort_t* hb   = (ushort_t*)(ws + 1 * MB);
  ushort_t* gib  = (ushort_t*)(ws + 9 * MB);
  ushort_t* ghb  = (ushort_t*)(ws + 21 * MB);
  ushort_t* Qb   = (ushort_t*)(ws + 5 * MB);
  ushort_t* Kb   = (ushort_t*)(ws + 9 * MB);
  ushort_t* Vt   = (ushort_t*)(ws + 13 * MB);
  ushort_t* ob   = (ushort_t*)(ws + 17 * MB);
  float*    y    = (float*)(ws + 21 * MB);
  ushort_t* ynb  = (ushort_t*)(ws + 29 * MB);
  ushort_t* gb   = (ushort_t*)(ws + 31 * MB);
  ushort_t* aggb = (ushort_t*)(ws + 29 * MB);
  float*    pf   = (float*)(ws + 21 * MB);
  float*    po0  = (float*)(ws + 21 * MB);         // [21,29) fp32 partial O
  float*    po1  = (float*)(ws + 33 * MB);         // [33,41) fp32 partial O
  float*    mlg  = (float*)(ws + 41 * MB);         // [41,41.25) m/l pairs
  ushort_t* xb   = (ushort_t*)(ws + 42 * MB);      // bf16 x [42,46)
  ushort_t* Wmsg_b = xb + 2097152;                 // weights bf16, contiguous
  ushort_t* Wih_b  = xb + 2359296;
  ushort_t* Whh_b  = xb + 3145728;
  ushort_t* Win_b  = xb + 3932160;
  ushort_t* Wout_b = xb + 4718592;
  ushort_t* Wlin_b = xb + 4980736;
  ushort_t* Wf1_b  = xb + 5242880;

  prep_kernel<<<4864, 256, 0, stream>>>(
      x, W_msg, W_ih, W_hh, W_in, W_out, W_lin, W_f1, xb, (float4*)agg);

  gemm_bt<MODE_MSG, 64><<<dim3(64, 8), 256, 0, stream>>>(
      xb, Wmsg_b, b_msg, H_N, nullptr, nullptr, edge, agg, nullptr,
      nullptr, nullptr, nullptr, nullptr);

  cvt_agg_kernel<<<1024, 256, 0, stream>>>(agg, aggb);

  gemm_bt<MODE_GI, 128><<<dim3(32, 24), 256, 0, stream>>>(
      aggb, Wih_b, b_ih, H_N, nullptr, gib, nullptr, nullptr, nullptr,
      nullptr, nullptr, nullptr, nullptr);

  gemm_bt<MODE_GH, 128><<<dim3(32, 24), 256, 0, stream>>>(
      xb, Whh_b, b_hh, H_N, nullptr, ghb, nullptr, nullptr, nullptr,
      nullptr, nullptr, nullptr, nullptr);

  gru_kernel<<<1024, 256, 0, stream>>>(gib, ghb, x, hb);

  gemm_bt<MODE_QKV, 128><<<dim3(32, 24), 256, 0, stream>>>(
      hb, Win_b, b_in, H_N, nullptr, nullptr, nullptr, nullptr, nullptr,
      Qb, Kb, Vt, nullptr);

  attn_kernel<<<512, 256, 0, stream>>>(Qb, Kb, Vt, po0, po1, mlg);

  amerge_kernel<<<1024, 256, 0, stream>>>(po0, po1, mlg, ob);

  gemm_bt<MODE_OUT, 64><<<dim3(64, 8), 256, 0, stream>>>(
      ob, Wout_b, b_out, H_N, y, nullptr, nullptr, nullptr, hb,
      nullptr, nullptr, nullptr, nullptr);

  ln_kernel<<<1024, 256, 0, stream>>>(y, ln_g, ln_b, ynb);

  gemm_bt<MODE_LIN, 64><<<dim3(64, 8), 256, 0, stream>>>(
      ynb, Wlin_b, b_lin, H_N, nullptr, gb, nullptr, nullptr, nullptr,
      nullptr, nullptr, nullptr, nullptr);

  gemm_bt<MODE_F1, 64><<<dim3(64, 16), 256, 0, stream>>>(
      gb, Wf1_b, b_f1, H_N, pf, nullptr, nullptr, nullptr, nullptr,
      nullptr, nullptr, nullptr, W_f2);

  f2red_kernel<<<16, 256, 0, stream>>>(pf, b_f2, (float*)d_out);
}

// Round 18
// 281.845 us; speedup vs baseline: 1.0589x; 1.0097x over previous
//
#include <hip/hip_runtime.h>

typedef unsigned short ushort_t;
typedef __attribute__((ext_vector_type(8))) short short8;
typedef __attribute__((ext_vector_type(4))) float float4v;

#define E_N   4096
#define H_N   512
#define NH_N  4
#define HD_N  128
#define FFN_N 1024
#define H3_N  1536

__device__ __forceinline__ float bf2f(ushort_t u) {
  union { unsigned u; float f; } v; v.u = ((unsigned)u) << 16; return v.f;
}
__device__ __forceinline__ ushort_t f2bf(float f) {
  union { float f; unsigned u; } v; v.f = f;
  unsigned r = v.u + 0x7fffu + ((v.u >> 16) & 1u);
  return (ushort_t)(r >> 16);
}
// base-2 exp: bare v_exp_f32 (S pre-scaled to log2 domain via QKV epilogue)
__device__ __forceinline__ float fexp2(float x) {
  return __builtin_amdgcn_exp2f(x);
}
// 8 consecutive fp32 -> 8 bf16 packed into uint4
__device__ __forceinline__ uint4 cvt8(const float* p) {
  float4 a = *(const float4*)p;
  float4 b = *(const float4*)(p + 4);
  union { ushort_t u[8]; uint4 v; } pk;
  pk.u[0] = f2bf(a.x); pk.u[1] = f2bf(a.y); pk.u[2] = f2bf(a.z); pk.u[3] = f2bf(a.w);
  pk.u[4] = f2bf(b.x); pk.u[5] = f2bf(b.y); pk.u[6] = f2bf(b.z); pk.u[7] = f2bf(b.w);
  return pk.v;
}

// global(16B/lane) -> LDS DMA: no VGPR payload (spill mechanism cannot occur)
__device__ __forceinline__ void gload16(const void* g, void* l) {
  __builtin_amdgcn_global_load_lds(
      (const __attribute__((address_space(1))) unsigned*)g,
      (__attribute__((address_space(3))) unsigned*)l, 16, 0, 0);
}

// ---------------------------------------------------------------------------
// prep: fused {zero agg (blocks 0..2047)} + {fp32->bf16 convert of x + all
// weights (blocks 2048..4863)}.
// ---------------------------------------------------------------------------
__global__ __launch_bounds__(256) void prep_kernel(
    const float* __restrict__ x,
    const float* __restrict__ wmsg, const float* __restrict__ wih,
    const float* __restrict__ whh,  const float* __restrict__ win,
    const float* __restrict__ wout, const float* __restrict__ wlin,
    const float* __restrict__ wf1,  ushort_t* __restrict__ dst,
    float4* __restrict__ agg)
{
  int b = blockIdx.x;
  if (b < 2048) {
    agg[(size_t)b * 256 + threadIdx.x] = make_float4(0.f, 0.f, 0.f, 0.f);
    return;
  }
  size_t o = ((size_t)(b - 2048) * 256 + threadIdx.x) * 8;
  const float* s;
  if      (o < 2097152) s = x    + o;
  else if (o < 2359296) s = wmsg + (o - 2097152);
  else if (o < 3145728) s = wih  + (o - 2359296);
  else if (o < 3932160) s = whh  + (o - 3145728);
  else if (o < 4718592) s = win  + (o - 3932160);
  else if (o < 4980736) s = wout + (o - 4718592);
  else if (o < 5242880) s = wlin + (o - 4980736);
  else                  s = wf1  + (o - 5242880);
  *(uint4*)(dst + o) = cvt8(s);
}

// agg fp32 -> bf16 (runs after MSG's atomics complete)
__global__ __launch_bounds__(256) void cvt_agg_kernel(
    const float* __restrict__ agg, ushort_t* __restrict__ aggb) {
  size_t o = ((size_t)blockIdx.x * 256 + threadIdx.x) * 8;
  *(uint4*)(aggb + o) = cvt8(agg + o);
}

// deterministic F1 reduce: out[row] = b2 + sum_k pf[row][k] (fixed order)
__global__ __launch_bounds__(256) void f2red_kernel(
    const float* __restrict__ pf, const float* __restrict__ b2,
    float* __restrict__ out) {
  int i = blockIdx.x * 256 + threadIdx.x;   // 0..4095
  float s = b2[0];
#pragma unroll
  for (int k = 0; k < 32; k++) s += pf[(size_t)i * 32 + k];
  out[i] = s;
}

// ---------------------------------------------------------------------------
// attn flash-merge: combine the two unnormalized KV-half partials (fp32,
// exact same math as the old in-LDS merge; fixed order -> deterministic).
// ---------------------------------------------------------------------------
__global__ __launch_bounds__(256) void amerge_kernel(
    const float* __restrict__ po0, const float* __restrict__ po1,
    const float* __restrict__ mlg, ushort_t* __restrict__ ob) {
  int t = blockIdx.x * 256 + threadIdx.x;       // E*H/8 threads
  int row = t >> 6;
  int c8  = (t & 63) * 8;
  int head = c8 >> 7;
  const float* p0 = mlg + ((size_t)(0 * 4 + head) * E_N + row) * 2;
  const float* p1 = mlg + ((size_t)(1 * 4 + head) * E_N + row) * 2;
  float m0 = p0[0], l0 = p0[1], m1 = p1[0], l1 = p1[1];
  float m  = fmaxf(m0, m1);
  float e0 = fexp2(m0 - m), e1 = fexp2(m1 - m);
  float inv = 1.f / (l0 * e0 + l1 * e1);
  float s0 = e0 * inv, s1 = e1 * inv;
  size_t off = (size_t)row * H_N + c8;
  float4 a0 = *(const float4*)(po0 + off);
  float4 a1 = *(const float4*)(po0 + off + 4);
  float4 b0 = *(const float4*)(po1 + off);
  float4 b1 = *(const float4*)(po1 + off + 4);
  union { ushort_t u[8]; uint4 v; } o;
  o.u[0] = f2bf(a0.x * s0 + b0.x * s1); o.u[1] = f2bf(a0.y * s0 + b0.y * s1);
  o.u[2] = f2bf(a0.z * s0 + b0.z * s1); o.u[3] = f2bf(a0.w * s0 + b0.w * s1);
  o.u[4] = f2bf(a1.x * s0 + b1.x * s1); o.u[5] = f2bf(a1.y * s0 + b1.y * s1);
  o.u[6] = f2bf(a1.z * s0 + b1.z * s1); o.u[7] = f2bf(a1.w * s0 + b1.w * s1);
  *(uint4*)(ob + off) = o.v;
}

// ---------------------------------------------------------------------------
// bf16-MFMA GEMM (DMA-staged): BM x 64 tile, BK=64, 4 waves,
// global_load_lds double-buffer, ONE barrier/iter, rule-#21 swizzle.
// BM=128 for wide GEMMs (grid.y=24), BM=64 for narrow N=512 GEMMs.
// MODE_QKV: q pre-scaled by log2e/sqrt(128) (exp2-domain softmax).
// MODE_F1: deterministic partial store (f2red sums in fixed order).
// ---------------------------------------------------------------------------
enum { MODE_MSG = 0, MODE_GI = 1, MODE_GH = 2, MODE_QKV = 3, MODE_OUT = 4,
       MODE_LIN = 5, MODE_F1 = 6 };

template <int MODE, int BM>
__global__ __launch_bounds__(256, (BM == 64 ? 4 : 3)) void gemm_bt(
    const ushort_t* __restrict__ A, const ushort_t* __restrict__ W,
    const float* __restrict__ bias, int K,
    float* __restrict__ outf, ushort_t* __restrict__ outb,
    const int* __restrict__ edge, float* __restrict__ aggf,
    const ushort_t* __restrict__ hres,
    ushort_t* __restrict__ qb, ushort_t* __restrict__ kb,
    ushort_t* __restrict__ vt, const float* __restrict__ wf2)
{
  constexpr int MI   = BM / 32;
  constexpr int ASZ  = BM * 128;
  constexpr int BSZ  = 64 * 128;
  constexpr int NCHA = BM / 8;
  constexpr int NCH  = NCHA + 8;

  __shared__ ushort_t As[2][BM * 64];
  __shared__ ushort_t Bs[2][64 * 64];

  const int tid  = threadIdx.x;
  const int lane = tid & 63;
  const int wave = tid >> 6;
  const int quad = lane >> 4;
  const int l15  = lane & 15;
  const int m0 = blockIdx.x * BM;
  const int n0 = blockIdx.y * 64;
  const int wm = (wave >> 1) * (BM / 2);
  const int wn = (wave & 1) * 32;
  const int rmask = (l15 & 7) << 4;

  const int crow  = lane >> 3;
  const int selem = ((((lane & 7) * 16)) ^ (crow << 4)) >> 1;

  float4v acc[MI][2];
#pragma unroll
  for (int i = 0; i < MI; i++)
#pragma unroll
    for (int j = 0; j < 2; j++)
#pragma unroll
      for (int r = 0; r < 4; r++) acc[i][j][r] = 0.f;

#define ISSUE(KK, BUF)                                                         \
  do {                                                                         \
    _Pragma("unroll")                                                          \
    for (int j_ = 0; j_ < NCH / 4; j_++) {                                     \
      const int c_ = wave + j_ * 4;                                            \
      if (c_ < NCHA) {                                                         \
        const int row_ = c_ * 8 + crow;                                        \
        gload16(A + (size_t)(m0 + row_) * K + (KK) + selem,                    \
                (char*)As + (BUF) * ASZ + c_ * 1024);                          \
      } else {                                                                 \
        const int row_ = (c_ - NCHA) * 8 + crow;                               \
        gload16(W + (size_t)(n0 + row_) * K + (KK) + selem,                    \
                (char*)Bs + (BUF) * BSZ + (c_ - NCHA) * 1024);                 \
      }                                                                        \
    }                                                                          \
  } while (0)

  ISSUE(0, 0);
  int cur = 0;

  for (int k0 = 0; k0 < K; k0 += 64) {
    __syncthreads();
    if (k0 + 64 < K) ISSUE(k0 + 64, cur ^ 1);

#pragma unroll
    for (int ks = 0; ks < 2; ks++) {
      short8 af[MI], bfr[2];
#pragma unroll
      for (int i = 0; i < MI; i++)
        af[i] = *(const short8*)((char*)As + cur * ASZ +
                 (wm + i * 16 + l15) * 128 + ((ks * 64 + quad * 16) ^ rmask));
#pragma unroll
      for (int j = 0; j < 2; j++)
        bfr[j] = *(const short8*)((char*)Bs + cur * BSZ +
                 (wn + j * 16 + l15) * 128 + ((ks * 64 + quad * 16) ^ rmask));
#pragma unroll
      for (int i = 0; i < MI; i++)
#pragma unroll
        for (int j = 0; j < 2; j++)
          acc[i][j] = __builtin_amdgcn_mfma_f32_16x16x32_bf16(af[i], bfr[j],
                                                              acc[i][j], 0, 0, 0);
    }
    cur ^= 1;
  }
#undef ISSUE

  if constexpr (MODE == MODE_F1) {
    float fsum[MI][4];
#pragma unroll
    for (int i = 0; i < MI; i++)
#pragma unroll
      for (int r = 0; r < 4; r++) fsum[i][r] = 0.f;
#pragma unroll
    for (int j = 0; j < 2; j++) {
      const int col = n0 + wn + j * 16 + l15;
      const float bv = bias[col];
      const float wv = wf2[col];
#pragma unroll
      for (int i = 0; i < MI; i++)
#pragma unroll
        for (int r = 0; r < 4; r++)
          fsum[i][r] += fmaxf(acc[i][j][r] + bv, 0.f) * wv;
    }
#pragma unroll
    for (int i = 0; i < MI; i++)
#pragma unroll
      for (int r = 0; r < 4; r++) {
        float s = fsum[i][r];
        s += __shfl_xor(s, 1, 64); s += __shfl_xor(s, 2, 64);
        s += __shfl_xor(s, 4, 64); s += __shfl_xor(s, 8, 64);
        if (l15 == 0)
          outf[(size_t)(m0 + wm + i * 16 + quad * 4 + r) * 32 +
               blockIdx.y * 2 + (wave & 1)] = s;
      }
  } else {
#pragma unroll
    for (int j = 0; j < 2; j++) {
      const int col = n0 + wn + j * 16 + l15;
      const float bv = bias[col];
#pragma unroll
      for (int i = 0; i < MI; i++) {
#pragma unroll
        for (int r = 0; r < 4; r++) {
          const int row = m0 + wm + i * 16 + quad * 4 + r;
          float v = acc[i][j][r] + bv;
          if constexpr (MODE == MODE_MSG) {
            v = fmaxf(v, 0.f);
            const int dst = edge[E_N + row] & (E_N - 1);  // edge_index[1][row]
            atomicAdd(&aggf[(size_t)dst * H_N + col], v);
          } else if constexpr (MODE == MODE_GI || MODE == MODE_GH) {
            outb[(size_t)row * H3_N + col] = f2bf(v);
          } else if constexpr (MODE == MODE_QKV) {
            const int part = col >> 9;         // 0=q 1=k 2=v
            const int hh   = (col >> 7) & 3;
            const int d    = col & 127;
            // fold log2e/sqrt(128) into q: attn softmax runs in exp2 domain
            if (part == 0) v *= 0.12751749803605814f;
            const ushort_t bvv = f2bf(v);
            if (part == 0)      qb[((size_t)hh * E_N + row) * HD_N + d] = bvv;
            else if (part == 1) kb[((size_t)hh * E_N + row) * HD_N + d] = bvv;
            else                vt[((size_t)hh * HD_N + d) * E_N + row] = bvv;  // V^T
          } else if constexpr (MODE == MODE_OUT) {
            v += bf2f(hres[(size_t)row * H_N + col]);   // residual y = o + h
            outf[(size_t)row * H_N + col] = v;
          } else {  // MODE_LIN
            outb[(size_t)row * H_N + col] = f2bf(fmaxf(v, 0.f));
          }
        }
      }
    }
  }
}

// ---------------------------------------------------------------------------
// Flash attention v11 = r17 split structure + T5 s_setprio around MFMA
// clusters.  r17 created the m191-verified setprio regime: 2 INDEPENDENT
// blocks/CU at different phases -- the priority hint lets the CU scheduler
// favor the block issuing matrix ops over the partner's staging/softmax
// VALU.  (r16's 8-wave lockstep design was the m190 null regime.)
// 512 blocks (one per {q-tile, head, KV-half}), 4 waves, 72 KB LDS.
// DMA staging, rule-#21 swizzle, exp2 softmax, unnormalized fp32 partials.
// ---------------------------------------------------------------------------
__global__ __launch_bounds__(256, 2) void attn_kernel(
    const ushort_t* __restrict__ Qg, const ushort_t* __restrict__ Kg,
    const ushort_t* __restrict__ Vtg,
    float* __restrict__ po0, float* __restrict__ po1,
    float* __restrict__ mlg)
{
  const int bid  = blockIdx.x;
  const int head = bid & 3;
  const int half = (bid >> 2) & 1;
  const int qb0  = (bid >> 3) * 64;
  const int tid  = threadIdx.x;
  const int wave = tid >> 6;      // 0..3: Q sub-tile + staging chunk set
  const int lane = tid & 63;
  const int quad = lane >> 4;
  const int l15  = lane & 15;

  __shared__ ushort_t Ks[2][64][128];   // dbuf, swizzled, 32768 B
  __shared__ ushort_t Vs[2][128][64];   // dbuf, swizzled, 32768 B
  __shared__ ushort_t Ps[4][16][64];    // per-wave, swizzled, 8192 B
  char* Psc = (char*)Ps + wave * 2048;

  const ushort_t* Qhead  = Qg  + (size_t)head * E_N * HD_N;
  const ushort_t* Khead  = Kg  + (size_t)head * E_N * HD_N;
  const ushort_t* Vthead = Vtg + (size_t)head * HD_N * E_N;

  // Q A-fragments: loop-invariant, in registers (pre-scaled, log2 domain).
  short8 aq[4];
#pragma unroll
  for (int ks = 0; ks < 4; ks++)
    aq[ks] = *(const short8*)(Qhead +
        (size_t)(qb0 + wave * 16 + l15) * HD_N + ks * 32 + quad * 8);

  float4v oacc[8];
#pragma unroll
  for (int i = 0; i < 8; i++)
#pragma unroll
    for (int r = 0; r < 4; r++) oacc[i][r] = 0.f;
  float mprev[4], lsum[4];
#pragma unroll
  for (int r = 0; r < 4; r++) { mprev[r] = -1e30f; lsum[r] = 0.f; }

  const int q15sw = (l15 & 7) << 4;           // read-side swizzle mask
  const int kt0 = half * 2048;

#define ISSUE(KT, BUF)                                                         \
  do {                                                                         \
    char* kb_ = (char*)Ks + ((BUF) << 14);                                     \
    char* vb_ = (char*)Vs + ((BUF) << 14);                                     \
    _Pragma("unroll")                                                          \
    for (int i_ = 0; i_ < 4; i_++) {                                           \
      const int c_ = wave * 4 + i_;                                            \
      const int krow_ = 4 * c_ + (lane >> 4);      /* tile row 0..63 */        \
      gload16(Khead + (size_t)((KT) + krow_) * HD_N +                          \
                  (((((lane & 15) * 16)) ^ ((krow_ & 7) << 4)) >> 1),          \
              kb_ + c_ * 1024);                                                \
      const int vrow_ = 8 * c_ + (lane >> 3);      /* tile row 0..127 */       \
      gload16(Vthead + (size_t)vrow_ * E_N + (KT) +                            \
                  (((((lane & 7) * 16)) ^ ((lane >> 3) << 4)) >> 1),           \
              vb_ + c_ * 1024);                                                \
    }                                                                          \
  } while (0)

  ISSUE(kt0, 0);   // prologue: tile 0
  int cur = 0;

  for (int it = 0; it < 32; it++) {
    __syncthreads();   // drains DMA (tile it ready) + tile it-1 reads done
    if (it + 1 < 32) ISSUE(kt0 + (it + 1) * 64, cur ^ 1);

    const char* kt_ = (char*)Ks + (cur << 14);
    const char* vt_ = (char*)Vs + (cur << 14);

    float4v sacc[4];
#pragma unroll
    for (int j = 0; j < 4; j++)
#pragma unroll
      for (int r = 0; r < 4; r++) sacc[j][r] = 0.f;
    __builtin_amdgcn_s_setprio(1);
#pragma unroll
    for (int ks = 0; ks < 4; ks++) {
#pragma unroll
      for (int j = 0; j < 4; j++) {
        short8 bk = *(const short8*)(kt_ + (j * 16 + l15) * 256 +
                                     ((ks * 64 + quad * 16) ^ q15sw));
        sacc[j] = __builtin_amdgcn_mfma_f32_16x16x32_bf16(aq[ks], bk, sacc[j], 0, 0, 0);
      }
    }
    __builtin_amdgcn_s_setprio(0);

    float alpha[4], pv[4][4];
#pragma unroll
    for (int r = 0; r < 4; r++) {
      float mx = -1e30f;
#pragma unroll
      for (int j = 0; j < 4; j++) { float s = sacc[j][r]; pv[j][r] = s; mx = fmaxf(mx, s); }
#pragma unroll
      for (int off = 1; off < 16; off <<= 1) mx = fmaxf(mx, __shfl_xor(mx, off, 64));
      float mnew = fmaxf(mprev[r], mx);
      alpha[r] = fexp2(mprev[r] - mnew);
      float ss = 0.f;
#pragma unroll
      for (int j = 0; j < 4; j++) { float p = fexp2(pv[j][r] - mnew); pv[j][r] = p; ss += p; }
#pragma unroll
      for (int off = 1; off < 16; off <<= 1) ss += __shfl_xor(ss, off, 64);
      lsum[r] = lsum[r] * alpha[r] + ss;
      mprev[r] = mnew;
    }
#pragma unroll
    for (int i = 0; i < 8; i++)
#pragma unroll
      for (int r = 0; r < 4; r++) oacc[i][r] *= alpha[r];

    // Ps write (wave-private, swizzled): within-wave lgkmcnt order, no barrier
#pragma unroll
    for (int j = 0; j < 4; j++)
#pragma unroll
      for (int r = 0; r < 4; r++) {
        const int prow = quad * 4 + r;
        *(ushort_t*)(Psc + prow * 128 +
                     ((2 * (j * 16 + l15)) ^ ((prow & 7) << 4))) = f2bf(pv[j][r]);
      }

    __builtin_amdgcn_s_setprio(1);
#pragma unroll
    for (int ks2 = 0; ks2 < 2; ks2++) {
      short8 ap = *(const short8*)(Psc + l15 * 128 +
                                   ((ks2 * 64 + quad * 16) ^ q15sw));
#pragma unroll
      for (int j = 0; j < 8; j++) {
        short8 bv = *(const short8*)(vt_ + (j * 16 + l15) * 128 +
                                     ((ks2 * 64 + quad * 16) ^ q15sw));
        oacc[j] = __builtin_amdgcn_mfma_f32_16x16x32_bf16(ap, bv, oacc[j], 0, 0, 0);
      }
    }
    __builtin_amdgcn_s_setprio(0);
    cur ^= 1;
  }
#undef ISSUE

  // ---- epilogue: unnormalized fp32 partial O + (m,l) to workspace ----
  float* pob = half ? po1 : po0;
#pragma unroll
  for (int j = 0; j < 8; j++)
#pragma unroll
    for (int r = 0; r < 4; r++) {
      const int row = qb0 + wave * 16 + quad * 4 + r;
      const int col = head * HD_N + j * 16 + l15;
      pob[(size_t)row * H_N + col] = oacc[j][r];
    }
  if (l15 == 0) {
#pragma unroll
    for (int r = 0; r < 4; r++) {
      const int row = qb0 + wave * 16 + quad * 4 + r;
      float* mlp = mlg + ((size_t)(half * 4 + head) * E_N + row) * 2;
      mlp[0] = mprev[r];
      mlp[1] = lsum[r];
    }
  }
}

// ---------------------------------------------------------------------------
// GRU elementwise, vectorized: each thread handles 8 contiguous cols.
__global__ __launch_bounds__(256) void gru_kernel(
    const ushort_t* __restrict__ gib, const ushort_t* __restrict__ ghb,
    const float* __restrict__ x, ushort_t* __restrict__ hb) {
  int t = blockIdx.x * 256 + threadIdx.x;         // E*H/8 threads
  int e = t >> 6, j8 = (t & 63) * 8;
  size_t b = (size_t)e * H3_N + j8;
  short8 vir = *(const short8*)(gib + b);
  short8 viz = *(const short8*)(gib + b + 512);
  short8 vin = *(const short8*)(gib + b + 1024);
  short8 vhr = *(const short8*)(ghb + b);
  short8 vhz = *(const short8*)(ghb + b + 512);
  short8 vhn = *(const short8*)(ghb + b + 1024);
  size_t xo = (size_t)e * H_N + j8;
  float4 x0 = *(const float4*)(x + xo);
  float4 x1 = *(const float4*)(x + xo + 4);
  float xv[8] = {x0.x, x0.y, x0.z, x0.w, x1.x, x1.y, x1.z, x1.w};
  union { ushort_t u[8]; uint4 v; } o;
#pragma unroll
  for (int i = 0; i < 8; i++) {
    float ir = bf2f((ushort_t)vir[i]), iz = bf2f((ushort_t)viz[i]), inn = bf2f((ushort_t)vin[i]);
    float hr = bf2f((ushort_t)vhr[i]), hz = bf2f((ushort_t)vhz[i]), hn  = bf2f((ushort_t)vhn[i]);
    float r = 1.f / (1.f + __expf(-(ir + hr)));
    float z = 1.f / (1.f + __expf(-(iz + hz)));
    float n = tanhf(inn + r * hn);
    o.u[i] = f2bf((1.f - z) * n + z * xv[i]);
  }
  *(uint4*)(hb + xo) = o.v;
}

__global__ __launch_bounds__(256) void ln_kernel(
    const float* __restrict__ y, const float* __restrict__ g,
    const float* __restrict__ b, ushort_t* __restrict__ yn) {
  int wave = threadIdx.x >> 6, lane = threadIdx.x & 63;
  int row = blockIdx.x * 4 + wave;
  const float* yr = y + (size_t)row * H_N;
  float v[8], s = 0.f;
#pragma unroll
  for (int i = 0; i < 8; i++) { v[i] = yr[lane + i * 64]; s += v[i]; }
#pragma unroll
  for (int off = 1; off < 64; off <<= 1) s += __shfl_xor(s, off, 64);
  float mu = s * (1.f / 512.f);
  float q = 0.f;
#pragma unroll
  for (int i = 0; i < 8; i++) { float d = v[i] - mu; q += d * d; }
#pragma unroll
  for (int off = 1; off < 64; off <<= 1) q += __shfl_xor(q, off, 64);
  float rstd = rsqrtf(q * (1.f / 512.f) + 1e-5f);
#pragma unroll
  for (int i = 0; i < 8; i++) {
    int c = lane + i * 64;
    yn[(size_t)row * H_N + c] = f2bf((v[i] - mu) * rstd * g[c] + b[c]);
  }
}

// ---------------------------------------------------------------------------
extern "C" void kernel_launch(void* const* d_in, const int* in_sizes, int n_in,
                              void* d_out, int out_size, void* d_ws, size_t ws_size,
                              hipStream_t stream) {
  const float* x     = (const float*)d_in[0];
  const int*   edge  = (const int*)d_in[1];
  const float* W_msg = (const float*)d_in[2];
  const float* b_msg = (const float*)d_in[3];
  const float* W_ih  = (const float*)d_in[4];
  const float* b_ih  = (const float*)d_in[5];
  const float* W_hh  = (const float*)d_in[6];
  const float* b_hh  = (const float*)d_in[7];
  const float* W_in  = (const float*)d_in[8];
  const float* b_in  = (const float*)d_in[9];
  const float* W_out = (const float*)d_in[10];
  const float* b_out = (const float*)d_in[11];
  const float* ln_g  = (const float*)d_in[12];
  const float* ln_b  = (const float*)d_in[13];
  const float* W_lin = (const float*)d_in[14];
  const float* b_lin = (const float*)d_in[15];
  const float* W_f1  = (const float*)d_in[16];
  const float* b_f1  = (const float*)d_in[17];
  const float* W_f2  = (const float*)d_in[18];
  const float* b_f2  = (const float*)d_in[19];

  char* ws = (char*)d_ws;
  const size_t MB = 1024 * 1024;
  // Workspace (liveness-audited, r17-exact).
  float*    agg  = (float*)(ws + 1 * MB);
  ushort_t* hb   = (ushort_t*)(ws + 1 * MB);
  ushort_t* gib  = (ushort_t*)(ws + 9 * MB);
  ushort_t* ghb  = (ushort_t*)(ws + 21 * MB);
  ushort_t* Qb   = (ushort_t*)(ws + 5 * MB);
  ushort_t* Kb   = (ushort_t*)(ws + 9 * MB);
  ushort_t* Vt   = (ushort_t*)(ws + 13 * MB);
  ushort_t* ob   = (ushort_t*)(ws + 17 * MB);
  float*    y    = (float*)(ws + 21 * MB);
  ushort_t* ynb  = (ushort_t*)(ws + 29 * MB);
  ushort_t* gb   = (ushort_t*)(ws + 31 * MB);
  ushort_t* aggb = (ushort_t*)(ws + 29 * MB);
  float*    pf   = (float*)(ws + 21 * MB);
  float*    po0  = (float*)(ws + 21 * MB);         // [21,29) fp32 partial O
  float*    po1  = (float*)(ws + 33 * MB);         // [33,41) fp32 partial O
  float*    mlg  = (float*)(ws + 41 * MB);         // [41,41.25) m/l pairs
  ushort_t* xb   = (ushort_t*)(ws + 42 * MB);      // bf16 x [42,46)
  ushort_t* Wmsg_b = xb + 2097152;                 // weights bf16, contiguous
  ushort_t* Wih_b  = xb + 2359296;
  ushort_t* Whh_b  = xb + 3145728;
  ushort_t* Win_b  = xb + 3932160;
  ushort_t* Wout_b = xb + 4718592;
  ushort_t* Wlin_b = xb + 4980736;
  ushort_t* Wf1_b  = xb + 5242880;

  prep_kernel<<<4864, 256, 0, stream>>>(
      x, W_msg, W_ih, W_hh, W_in, W_out, W_lin, W_f1, xb, (float4*)agg);

  gemm_bt<MODE_MSG, 64><<<dim3(64, 8), 256, 0, stream>>>(
      xb, Wmsg_b, b_msg, H_N, nullptr, nullptr, edge, agg, nullptr,
      nullptr, nullptr, nullptr, nullptr);

  cvt_agg_kernel<<<1024, 256, 0, stream>>>(agg, aggb);

  gemm_bt<MODE_GI, 128><<<dim3(32, 24), 256, 0, stream>>>(
      aggb, Wih_b, b_ih, H_N, nullptr, gib, nullptr, nullptr, nullptr,
      nullptr, nullptr, nullptr, nullptr);

  gemm_bt<MODE_GH, 128><<<dim3(32, 24), 256, 0, stream>>>(
      xb, Whh_b, b_hh, H_N, nullptr, ghb, nullptr, nullptr, nullptr,
      nullptr, nullptr, nullptr, nullptr);

  gru_kernel<<<1024, 256, 0, stream>>>(gib, ghb, x, hb);

  gemm_bt<MODE_QKV, 128><<<dim3(32, 24), 256, 0, stream>>>(
      hb, Win_b, b_in, H_N, nullptr, nullptr, nullptr, nullptr, nullptr,
      Qb, Kb, Vt, nullptr);

  attn_kernel<<<512, 256, 0, stream>>>(Qb, Kb, Vt, po0, po1, mlg);

  amerge_kernel<<<1024, 256, 0, stream>>>(po0, po1, mlg, ob);

  gemm_bt<MODE_OUT, 64><<<dim3(64, 8), 256, 0, stream>>>(
      ob, Wout_b, b_out, H_N, y, nullptr, nullptr, nullptr, hb,
      nullptr, nullptr, nullptr, nullptr);

  ln_kernel<<<1024, 256, 0, stream>>>(y, ln_g, ln_b, ynb);

  gemm_bt<MODE_LIN, 64><<<dim3(64, 8), 256, 0, stream>>>(
      ynb, Wlin_b, b_lin, H_N, nullptr, gb, nullptr, nullptr, nullptr,
      nullptr, nullptr, nullptr, nullptr);

  gemm_bt<MODE_F1, 64><<<dim3(64, 16), 256, 0, stream>>>(
      gb, Wf1_b, b_f1, H_N, pf, nullptr, nullptr, nullptr, nullptr,
      nullptr, nullptr, nullptr, W_f2);

  f2red_kernel<<<16, 256, 0, stream>>>(pf, b_f2, (float*)d_out);
}